// Round 1
// baseline (2688.263 us; speedup 1.0000x reference)
//
#include <hip/hip_runtime.h>
#include <math.h>

#define HD   64
#define NPIX 9216
#define QT   64
#define MK   128
#define NCH  (NPIX / MK)   // 72
#define K9   9

__device__ __forceinline__ void topk_insert(float (&tv)[K9], int (&ti)[K9], float s, int m) {
  float cv = s; int ci = m;
  #pragma unroll
  for (int r = 0; r < K9; ++r) {
    if (cv > tv[r]) {               // strict >: earlier index wins on ties
      float t = tv[r]; tv[r] = cv; cv = t;
      int   u = ti[r]; ti[r] = ci; ci = u;
    }
  }
}

__global__ __launch_bounds__(256, 2)
void topk_attn(const float* __restrict__ Qg, const float* __restrict__ Kg,
               const float* __restrict__ Vg, float* __restrict__ Og) {
  // LDS: 16KB + 32KB + 32KB = 80KB -> 2 WG/CU on gfx950 (160KB LDS)
  __shared__ __align__(16) float Qs[HD * QT];    // [c][q]
  __shared__ __align__(16) float KsL[HD * MK];   // [c][m]
  __shared__ __align__(16) float Ss[QT * MK];    // [q][key, xor-swizzled float4 blocks]

  const int tid = threadIdx.x;
  const int b  = blockIdx.y;
  const int n0 = blockIdx.x * QT;

  const float* qb = Qg + (size_t)b * HD * NPIX;
  const float* kb = Kg + (size_t)b * HD * NPIX;
  const float* vb = Vg + (size_t)b * HD * NPIX;

  // ---- load Q tile: rows c=0..63, cols = queries n0..n0+63 (coalesced) ----
  {
    const int l16 = tid & 15, rg = tid >> 4;
    #pragma unroll
    for (int i = 0; i < 4; ++i) {
      const int r = rg * 4 + i;
      *reinterpret_cast<float4*>(&Qs[r * QT + l16 * 4]) =
        *reinterpret_cast<const float4*>(qb + (size_t)r * NPIX + n0 + l16 * 4);
    }
  }

  const int lane = tid & 31, rgrp = tid >> 5;
  float4 stg[8];
  // ---- first K chunk ----
  #pragma unroll
  for (int i = 0; i < 8; ++i) {
    const int r = rgrp * 8 + i;
    stg[i] = *reinterpret_cast<const float4*>(kb + (size_t)r * NPIX + lane * 4);
  }
  #pragma unroll
  for (int i = 0; i < 8; ++i) {
    const int r = rgrp * 8 + i;
    *reinterpret_cast<float4*>(&KsL[r * MK + lane * 4]) = stg[i];
  }

  // ---- per-thread top-9 state (thread scans its own key subsequence in order) ----
  float tval[K9]; int tidx[K9];
  #pragma unroll
  for (int r = 0; r < K9; ++r) { tval[r] = -3.4e38f; tidx[r] = 0; }

  const int qg  = tid >> 5;   // 0..7  (8 queries each)
  const int kgp = tid & 31;   // 0..31 (4 keys each)
  const int sq  = tid >> 2;   // scan: query row 0..63
  const int sp  = tid & 3;    // scan: part 0..3 (32 keys each)

  for (int ch = 0; ch < NCH; ++ch) {
    __syncthreads();  // KsL ready (prev iter's stores), Ss free (prev scan done)

    float acc[8][4];
    #pragma unroll
    for (int i = 0; i < 8; ++i)
      #pragma unroll
      for (int j = 0; j < 4; ++j) acc[i][j] = 0.f;

    #pragma unroll 4
    for (int c = 0; c < HD; ++c) {
      const float4 a0 = *reinterpret_cast<const float4*>(&Qs[c * QT + qg * 8]);
      const float4 a1 = *reinterpret_cast<const float4*>(&Qs[c * QT + qg * 8 + 4]);
      const float4 kk = *reinterpret_cast<const float4*>(&KsL[c * MK + kgp * 4]);
      const float qv[8] = {a0.x,a0.y,a0.z,a0.w,a1.x,a1.y,a1.z,a1.w};
      const float kv[4] = {kk.x,kk.y,kk.z,kk.w};
      #pragma unroll
      for (int i = 0; i < 8; ++i)
        #pragma unroll
        for (int j = 0; j < 4; ++j)
          acc[i][j] = fmaf(qv[i], kv[j], acc[i][j]);
    }

    // write scores (x8 = /SCALE), xor-swizzled so the scan isn't same-bank
    #pragma unroll
    for (int i = 0; i < 8; ++i) {
      const int r  = qg * 8 + i;
      const int f4 = kgp ^ (r & 7);
      *reinterpret_cast<float4*>(&Ss[r * MK + f4 * 4]) =
        make_float4(acc[i][0]*8.f, acc[i][1]*8.f, acc[i][2]*8.f, acc[i][3]*8.f);
    }

    __syncthreads();  // Ss ready; KsL fully consumed

    // issue next K-chunk global loads now; L2 latency hides under the scan
    const bool more = (ch + 1 < NCH);
    if (more) {
      const int m0 = (ch + 1) * MK;
      #pragma unroll
      for (int i = 0; i < 8; ++i) {
        const int r = rgrp * 8 + i;
        stg[i] = *reinterpret_cast<const float4*>(kb + (size_t)r * NPIX + m0 + lane * 4);
      }
    }

    // scan this chunk's scores for my (query, part), ascending key index
    {
      const int mb = ch * MK;
      #pragma unroll
      for (int s8 = 0; s8 < 8; ++s8) {
        const int l  = sp * 8 + s8;
        const int f4 = l ^ (sq & 7);
        const float4 sv = *reinterpret_cast<const float4*>(&Ss[sq * MK + f4 * 4]);
        const int m = mb + l * 4;
        const float mx = fmaxf(fmaxf(sv.x, sv.y), fmaxf(sv.z, sv.w));
        if (mx > tval[K9-1]) {
          if (sv.x > tval[K9-1]) topk_insert(tval, tidx, sv.x, m);
          if (sv.y > tval[K9-1]) topk_insert(tval, tidx, sv.y, m+1);
          if (sv.z > tval[K9-1]) topk_insert(tval, tidx, sv.z, m+2);
          if (sv.w > tval[K9-1]) topk_insert(tval, tidx, sv.w, m+3);
        }
      }
    }

    if (more) {
      #pragma unroll
      for (int i = 0; i < 8; ++i) {
        const int r = rgrp * 8 + i;
        *reinterpret_cast<float4*>(&KsL[r * MK + lane * 4]) = stg[i];
      }
    }
  }

  __syncthreads();

  // ---- dump 4 partial top-9 lists per query (reuse KsL) ----
  float* Pv = KsL;                                  // 64*4*9 floats
  int*   Pi = reinterpret_cast<int*>(KsL) + QT*4*K9;
  {
    const int basep = (sq * 4 + sp) * K9;
    #pragma unroll
    for (int r = 0; r < K9; ++r) { Pv[basep + r] = tval[r]; Pi[basep + r] = tidx[r]; }
  }
  __syncthreads();

  // ---- 4-way merge + softmax, one thread per query (reuse Qs for w/idx) ----
  float* Wls = Qs;
  int*   Ils = reinterpret_cast<int*>(Qs) + QT * K9;
  if (tid < QT) {
    const int q = tid;
    int cp[4] = {0,0,0,0};
    float mv[K9]; int mi[K9];
    #pragma unroll
    for (int r = 0; r < K9; ++r) {
      float bv = -3.4e38f; int bi = 0x7fffffff; int bp = 0;
      #pragma unroll
      for (int p = 0; p < 4; ++p) {
        const int cc = cp[p];
        const float v = Pv[(q*4+p)*K9 + cc];
        const int  ii = Pi[(q*4+p)*K9 + cc];
        if (v > bv || (v == bv && ii < bi)) { bv = v; bi = ii; bp = p; }
      }
      mv[r] = bv; mi[r] = bi; cp[bp]++;
    }
    const float mmax = mv[0];
    float e[K9]; float ssum = 0.f;
    #pragma unroll
    for (int r = 0; r < K9; ++r) { e[r] = expf(mv[r] - mmax); ssum += e[r]; }
    const float inv = 1.f / ssum;
    #pragma unroll
    for (int r = 0; r < K9; ++r) { Wls[q*K9 + r] = e[r] * inv; Ils[q*K9 + r] = mi[r]; }
  }
  __syncthreads();

  // ---- gather V (L2-resident) and write output (coalesced) ----
  {
    const int q = tid >> 2, cg = tid & 3;
    float o[16];
    #pragma unroll
    for (int c = 0; c < 16; ++c) o[c] = 0.f;
    const float* vbase = vb + (size_t)(cg * 16) * NPIX;
    #pragma unroll
    for (int r = 0; r < K9; ++r) {
      const float w = Wls[q*K9 + r];
      const int   m = Ils[q*K9 + r];
      #pragma unroll
      for (int c = 0; c < 16; ++c)
        o[c] = fmaf(w, vbase[(size_t)c * NPIX + m], o[c]);
    }
    float* op = Og + ((size_t)b * NPIX + n0 + q) * HD + cg * 16;
    #pragma unroll
    for (int c4 = 0; c4 < 4; ++c4)
      *reinterpret_cast<float4*>(op + c4 * 4) =
        make_float4(o[c4*4], o[c4*4+1], o[c4*4+2], o[c4*4+3]);
  }
}

extern "C" void kernel_launch(void* const* d_in, const int* in_sizes, int n_in,
                              void* d_out, int out_size, void* d_ws, size_t ws_size,
                              hipStream_t stream) {
  const float* q = (const float*)d_in[0];
  const float* k = (const float*)d_in[1];
  const float* v = (const float*)d_in[2];
  float* o = (float*)d_out;
  dim3 grid(NPIX / QT, 4);   // 144 x 4 = 576 WGs
  topk_attn<<<grid, dim3(256), 0, stream>>>(q, k, v, o);
}

// Round 2
// 608.409 us; speedup vs baseline: 4.4185x; 4.4185x over previous
//
#include <hip/hip_runtime.h>
#include <math.h>

#define HD   64
#define NPIX 9216
#define B4   4
#define K9   9
#define QB   32              // queries per block (main kernel)
#define NQCH (NPIX / QB)     // 288
#define KQ   (NPIX / 4)      // 2304 keys per wave
#define NT   (KQ / 16)       // 144 key subtiles per wave

typedef __attribute__((ext_vector_type(8))) short bf16x8;
typedef __attribute__((ext_vector_type(4))) float f32x4;
typedef unsigned short ushort_t;

struct Frags { bf16x8 h0, h1, l0, l1; };

__device__ __forceinline__ ushort_t f2bf(float x) {
  unsigned u = __float_as_uint(x);
  unsigned r = (u + 0x7fffu + ((u >> 16) & 1u)) >> 16;   // RNE
  return (ushort_t)r;
}
__device__ __forceinline__ float bf2f(ushort_t h) {
  return __uint_as_float(((unsigned)h) << 16);
}

// ---------------- prep: transpose [b][d][n] -> [b][n][d], split bf16 hi/lo ----
__global__ __launch_bounds__(256) void prep_kernel(
    const float* __restrict__ qg, const float* __restrict__ kg,
    ushort_t* __restrict__ Qh, ushort_t* __restrict__ Ql,
    ushort_t* __restrict__ Kh, ushort_t* __restrict__ Kl) {
  __shared__ float Ts[64][65];
  const int b = blockIdx.y, n0 = blockIdx.x * 64, z = blockIdx.z;
  const float* src = z ? kg : qg;
  ushort_t* dh = z ? Kh : Qh;
  ushort_t* dl = z ? Kl : Ql;
  const float scale = z ? 1.f : 8.f;   // fold x8 (= /SCALE) into Q
  const int tid = threadIdx.x;
  #pragma unroll
  for (int i = 0; i < 16; ++i) {
    const int idx = i * 256 + tid, c = idx >> 6, nl = idx & 63;
    Ts[c][nl] = src[((size_t)b * HD + c) * NPIX + n0 + nl];
  }
  __syncthreads();
  #pragma unroll
  for (int i = 0; i < 16; ++i) {
    const int idx = i * 256 + tid, nl = idx >> 6, d = idx & 63;
    const float x = Ts[d][nl] * scale;
    const ushort_t hi = f2bf(x);
    const ushort_t lo = f2bf(x - bf2f(hi));
    const size_t o = ((size_t)b * NPIX + n0 + nl) * HD + d;
    dh[o] = hi; dl[o] = lo;
  }
}

// ---------------- helpers ----------------
__device__ __forceinline__ Frags ldfr(const ushort_t* __restrict__ ph,
                                      const ushort_t* __restrict__ pl,
                                      int row, int lg) {
  const size_t o = (size_t)row * HD + lg * 8;
  Frags f;
  f.h0 = *reinterpret_cast<const bf16x8*>(ph + o);
  f.h1 = *reinterpret_cast<const bf16x8*>(ph + o + 32);
  f.l0 = *reinterpret_cast<const bf16x8*>(pl + o);
  f.l1 = *reinterpret_cast<const bf16x8*>(pl + o + 32);
  return f;
}

__device__ __forceinline__ void ins9(float (&tv)[K9], int (&ti)[K9], float s, int m) {
  float cv = s; int ci = m;
  #pragma unroll
  for (int r = 0; r < K9; ++r) {
    const bool c = cv > tv[r];           // strict >: earlier (lower) index wins ties
    const float hv = c ? cv : tv[r];  const float lv = c ? tv[r] : cv;
    const int   hk = c ? ci : ti[r];  const int   lk = c ? ti[r] : ci;
    tv[r] = hv; ti[r] = hk; cv = lv; ci = lk;
  }
}

// ---------------- main: MFMA scores + per-lane top-9 + merge + softmax + V ----
__global__ __launch_bounds__(256, 3) void attn_main(
    const ushort_t* __restrict__ Qh, const ushort_t* __restrict__ Ql,
    const ushort_t* __restrict__ Kh, const ushort_t* __restrict__ Kl,
    const float* __restrict__ Vg, float* __restrict__ Og) {

  __shared__ float Pv[QB][16][K9];
  __shared__ int   Pi[QB][16][K9];
  __shared__ float Wls[QB][K9];
  __shared__ int   Ils[QB][K9];

  const int tid = threadIdx.x;
  const int w = tid >> 6, l = tid & 63, lg = l >> 4, lc = l & 15;
  const int b = blockIdx.y, qbase = blockIdx.x * QB;

  // Q fragments (B operand): col = lane&15 = query, k = 8*(lane>>4)+e
  const size_t qr0 = ((size_t)b * NPIX + qbase + lc) * HD + lg * 8;
  const size_t qr1 = qr0 + (size_t)16 * HD;
  Frags qf0, qf1;
  qf0.h0 = *reinterpret_cast<const bf16x8*>(Qh + qr0);
  qf0.h1 = *reinterpret_cast<const bf16x8*>(Qh + qr0 + 32);
  qf0.l0 = *reinterpret_cast<const bf16x8*>(Ql + qr0);
  qf0.l1 = *reinterpret_cast<const bf16x8*>(Ql + qr0 + 32);
  qf1.h0 = *reinterpret_cast<const bf16x8*>(Qh + qr1);
  qf1.h1 = *reinterpret_cast<const bf16x8*>(Qh + qr1 + 32);
  qf1.l0 = *reinterpret_cast<const bf16x8*>(Ql + qr1);
  qf1.l1 = *reinterpret_cast<const bf16x8*>(Ql + qr1 + 32);

  const ushort_t* kh = Kh + (size_t)b * NPIX * HD;
  const ushort_t* kl = Kl + (size_t)b * NPIX * HD;
  const int wbase = w * KQ;

  float tv0[K9], tv1[K9]; int ti0[K9], ti1[K9];
  #pragma unroll
  for (int r = 0; r < K9; ++r) { tv0[r] = -3.4e38f; tv1[r] = -3.4e38f; ti0[r] = 0; ti1[r] = 0; }

  auto scan4 = [&](const f32x4& s, int kb, float (&tv)[K9], int (&ti)[K9]) {
    const float m = fmaxf(fmaxf(s[0], s[1]), fmaxf(s[2], s[3]));
    if (m > tv[8]) {
      if (s[0] > tv[8]) ins9(tv, ti, s[0], kb);
      if (s[1] > tv[8]) ins9(tv, ti, s[1], kb + 1);
      if (s[2] > tv[8]) ins9(tv, ti, s[2], kb + 2);
      if (s[3] > tv[8]) ins9(tv, ti, s[3], kb + 3);
    }
  };

  auto step = [&](const Frags& a, int key0) {
    f32x4 acc0 = {0.f, 0.f, 0.f, 0.f};
    f32x4 acc1 = {0.f, 0.f, 0.f, 0.f};
    acc0 = __builtin_amdgcn_mfma_f32_16x16x32_bf16(a.h0, qf0.h0, acc0, 0, 0, 0);
    acc1 = __builtin_amdgcn_mfma_f32_16x16x32_bf16(a.h0, qf1.h0, acc1, 0, 0, 0);
    acc0 = __builtin_amdgcn_mfma_f32_16x16x32_bf16(a.h1, qf0.h1, acc0, 0, 0, 0);
    acc1 = __builtin_amdgcn_mfma_f32_16x16x32_bf16(a.h1, qf1.h1, acc1, 0, 0, 0);
    acc0 = __builtin_amdgcn_mfma_f32_16x16x32_bf16(a.l0, qf0.h0, acc0, 0, 0, 0);
    acc1 = __builtin_amdgcn_mfma_f32_16x16x32_bf16(a.l0, qf1.h0, acc1, 0, 0, 0);
    acc0 = __builtin_amdgcn_mfma_f32_16x16x32_bf16(a.l1, qf0.h1, acc0, 0, 0, 0);
    acc1 = __builtin_amdgcn_mfma_f32_16x16x32_bf16(a.l1, qf1.h1, acc1, 0, 0, 0);
    acc0 = __builtin_amdgcn_mfma_f32_16x16x32_bf16(a.h0, qf0.l0, acc0, 0, 0, 0);
    acc1 = __builtin_amdgcn_mfma_f32_16x16x32_bf16(a.h0, qf1.l0, acc1, 0, 0, 0);
    acc0 = __builtin_amdgcn_mfma_f32_16x16x32_bf16(a.h1, qf0.l1, acc0, 0, 0, 0);
    acc1 = __builtin_amdgcn_mfma_f32_16x16x32_bf16(a.h1, qf1.l1, acc1, 0, 0, 0);
    const int kb = key0 + lg * 4;   // C/D: row = (lane>>4)*4 + reg = key offset
    scan4(acc0, kb, tv0, ti0);
    scan4(acc1, kb, tv1, ti1);
  };

  // main loop: register-double-buffered A-frag loads straight from L2
  Frags fa = ldfr(kh, kl, wbase + lc, lg);
  for (int t = 0; t < NT; t += 2) {
    Frags fb = ldfr(kh, kl, wbase + (t + 1) * 16 + lc, lg);
    step(fa, wbase + t * 16);
    const int tn = (t + 2 < NT) ? (t + 2) : 0;   // dummy reload at end, discarded
    Frags fc = ldfr(kh, kl, wbase + tn * 16 + lc, lg);
    step(fb, wbase + (t + 1) * 16);
    fa = fc;
  }

  // ---- dump 16 partial lists per query ----
  #pragma unroll
  for (int r = 0; r < K9; ++r) {
    Pv[lc][w * 4 + lg][r] = tv0[r];  Pi[lc][w * 4 + lg][r] = ti0[r];
    Pv[16 + lc][w * 4 + lg][r] = tv1[r];  Pi[16 + lc][w * 4 + lg][r] = ti1[r];
  }
  __syncthreads();

  // ---- stage A: 128 threads, each merges 4 sorted lists -> 1 ----
  float mvA[K9]; int miA[K9];
  const int qlA = tid >> 2, quA = tid & 3;
  if (tid < 128) {
    int cp[4] = {0, 0, 0, 0};
    #pragma unroll
    for (int r = 0; r < K9; ++r) {
      float bv = -3.4e38f; int bi = 0x7fffffff, bp = 0;
      #pragma unroll
      for (int p = 0; p < 4; ++p) {
        const float v = Pv[qlA][quA * 4 + p][cp[p]];
        const int   i = Pi[qlA][quA * 4 + p][cp[p]];
        if (v > bv || (v == bv && i < bi)) { bv = v; bi = i; bp = p; }
      }
      mvA[r] = bv; miA[r] = bi; cp[bp]++;
    }
  }
  __syncthreads();
  if (tid < 128) {
    #pragma unroll
    for (int r = 0; r < K9; ++r) { Pv[qlA][quA][r] = mvA[r]; Pi[qlA][quA][r] = miA[r]; }
  }
  __syncthreads();

  // ---- stage B: 32 threads, final merge + softmax ----
  if (tid < QB) {
    const int q = tid;
    int cp[4] = {0, 0, 0, 0};
    float mv[K9]; int mi[K9];
    #pragma unroll
    for (int r = 0; r < K9; ++r) {
      float bv = -3.4e38f; int bi = 0x7fffffff, bp = 0;
      #pragma unroll
      for (int p = 0; p < 4; ++p) {
        const float v = Pv[q][p][cp[p]];
        const int   i = Pi[q][p][cp[p]];
        if (v > bv || (v == bv && i < bi)) { bv = v; bi = i; bp = p; }
      }
      mv[r] = bv; mi[r] = bi; cp[bp]++;
    }
    const float mmax = mv[0];
    float e[K9]; float ssum = 0.f;
    #pragma unroll
    for (int r = 0; r < K9; ++r) { e[r] = expf(mv[r] - mmax); ssum += e[r]; }
    const float inv = 1.f / ssum;
    #pragma unroll
    for (int r = 0; r < K9; ++r) { Wls[q][r] = e[r] * inv; Ils[q][r] = mi[r]; }
  }
  __syncthreads();

  // ---- V gather + output ----
  {
    const float* vb = Vg + (size_t)b * HD * NPIX;
    const int qloc = tid >> 3, cg = tid & 7;
    float o[8];
    #pragma unroll
    for (int c = 0; c < 8; ++c) o[c] = 0.f;
    #pragma unroll
    for (int r = 0; r < K9; ++r) {
      const float wgt = Wls[qloc][r];
      const int   m   = Ils[qloc][r];
      #pragma unroll
      for (int c = 0; c < 8; ++c)
        o[c] = fmaf(wgt, vb[(size_t)(cg * 8 + c) * NPIX + m], o[c]);
    }
    float* op = Og + (((size_t)b * NPIX) + qbase + qloc) * HD + cg * 8;
    *reinterpret_cast<float4*>(op)     = make_float4(o[0], o[1], o[2], o[3]);
    *reinterpret_cast<float4*>(op + 4) = make_float4(o[4], o[5], o[6], o[7]);
  }
}

// ================= fallback (round-1 fp32 kernel, used if ws too small) =======
__device__ __forceinline__ void topk_insert_fb(float (&tv)[K9], int (&ti)[K9], float s, int m) {
  float cv = s; int ci = m;
  #pragma unroll
  for (int r = 0; r < K9; ++r) {
    if (cv > tv[r]) {
      float t = tv[r]; tv[r] = cv; cv = t;
      int   u = ti[r]; ti[r] = ci; ci = u;
    }
  }
}

#define QT 64
#define MK 128
#define NCHF (NPIX / MK)

__global__ __launch_bounds__(256, 2)
void topk_attn_fb(const float* __restrict__ Qg, const float* __restrict__ Kg,
                  const float* __restrict__ Vg, float* __restrict__ Og) {
  __shared__ __align__(16) float Qs[HD * QT];
  __shared__ __align__(16) float KsL[HD * MK];
  __shared__ __align__(16) float Ss[QT * MK];
  const int tid = threadIdx.x;
  const int b = blockIdx.y;
  const int n0 = blockIdx.x * QT;
  const float* qb = Qg + (size_t)b * HD * NPIX;
  const float* kb = Kg + (size_t)b * HD * NPIX;
  const float* vb = Vg + (size_t)b * HD * NPIX;
  {
    const int l16 = tid & 15, rg = tid >> 4;
    #pragma unroll
    for (int i = 0; i < 4; ++i) {
      const int r = rg * 4 + i;
      *reinterpret_cast<float4*>(&Qs[r * QT + l16 * 4]) =
        *reinterpret_cast<const float4*>(qb + (size_t)r * NPIX + n0 + l16 * 4);
    }
  }
  const int lane = tid & 31, rgrp = tid >> 5;
  float4 stg[8];
  #pragma unroll
  for (int i = 0; i < 8; ++i) {
    const int r = rgrp * 8 + i;
    stg[i] = *reinterpret_cast<const float4*>(kb + (size_t)r * NPIX + lane * 4);
  }
  #pragma unroll
  for (int i = 0; i < 8; ++i) {
    const int r = rgrp * 8 + i;
    *reinterpret_cast<float4*>(&KsL[r * MK + lane * 4]) = stg[i];
  }
  float tval[K9]; int tidx[K9];
  #pragma unroll
  for (int r = 0; r < K9; ++r) { tval[r] = -3.4e38f; tidx[r] = 0; }
  const int qg = tid >> 5;
  const int kgp = tid & 31;
  const int sq = tid >> 2;
  const int sp = tid & 3;
  for (int ch = 0; ch < NCHF; ++ch) {
    __syncthreads();
    float acc[8][4];
    #pragma unroll
    for (int i = 0; i < 8; ++i)
      #pragma unroll
      for (int j = 0; j < 4; ++j) acc[i][j] = 0.f;
    #pragma unroll 4
    for (int c = 0; c < HD; ++c) {
      const float4 a0 = *reinterpret_cast<const float4*>(&Qs[c * QT + qg * 8]);
      const float4 a1 = *reinterpret_cast<const float4*>(&Qs[c * QT + qg * 8 + 4]);
      const float4 kk = *reinterpret_cast<const float4*>(&KsL[c * MK + kgp * 4]);
      const float qv[8] = {a0.x, a0.y, a0.z, a0.w, a1.x, a1.y, a1.z, a1.w};
      const float kv[4] = {kk.x, kk.y, kk.z, kk.w};
      #pragma unroll
      for (int i = 0; i < 8; ++i)
        #pragma unroll
        for (int j = 0; j < 4; ++j)
          acc[i][j] = fmaf(qv[i], kv[j], acc[i][j]);
    }
    #pragma unroll
    for (int i = 0; i < 8; ++i) {
      const int r = qg * 8 + i;
      const int f4 = kgp ^ (r & 7);
      *reinterpret_cast<float4*>(&Ss[r * MK + f4 * 4]) =
        make_float4(acc[i][0] * 8.f, acc[i][1] * 8.f, acc[i][2] * 8.f, acc[i][3] * 8.f);
    }
    __syncthreads();
    const bool more = (ch + 1 < NCHF);
    if (more) {
      const int m0 = (ch + 1) * MK;
      #pragma unroll
      for (int i = 0; i < 8; ++i) {
        const int r = rgrp * 8 + i;
        stg[i] = *reinterpret_cast<const float4*>(kb + (size_t)r * NPIX + m0 + lane * 4);
      }
    }
    {
      const int mb = ch * MK;
      #pragma unroll
      for (int s8 = 0; s8 < 8; ++s8) {
        const int ll = sp * 8 + s8;
        const int f4 = ll ^ (sq & 7);
        const float4 sv = *reinterpret_cast<const float4*>(&Ss[sq * MK + f4 * 4]);
        const int m = mb + ll * 4;
        const float mx = fmaxf(fmaxf(sv.x, sv.y), fmaxf(sv.z, sv.w));
        if (mx > tval[K9 - 1]) {
          if (sv.x > tval[K9 - 1]) topk_insert_fb(tval, tidx, sv.x, m);
          if (sv.y > tval[K9 - 1]) topk_insert_fb(tval, tidx, sv.y, m + 1);
          if (sv.z > tval[K9 - 1]) topk_insert_fb(tval, tidx, sv.z, m + 2);
          if (sv.w > tval[K9 - 1]) topk_insert_fb(tval, tidx, sv.w, m + 3);
        }
      }
    }
    if (more) {
      #pragma unroll
      for (int i = 0; i < 8; ++i) {
        const int r = rgrp * 8 + i;
        *reinterpret_cast<float4*>(&KsL[r * MK + lane * 4]) = stg[i];
      }
    }
  }
  __syncthreads();
  float* Pvf = KsL;
  int* Pif = reinterpret_cast<int*>(KsL) + QT * 4 * K9;
  {
    const int basep = (sq * 4 + sp) * K9;
    #pragma unroll
    for (int r = 0; r < K9; ++r) { Pvf[basep + r] = tval[r]; Pif[basep + r] = tidx[r]; }
  }
  __syncthreads();
  float* Wlsf = Qs;
  int* Ilsf = reinterpret_cast<int*>(Qs) + QT * K9;
  if (tid < QT) {
    const int q = tid;
    int cp[4] = {0, 0, 0, 0};
    float mv[K9]; int mi[K9];
    #pragma unroll
    for (int r = 0; r < K9; ++r) {
      float bv = -3.4e38f; int bi = 0x7fffffff; int bp = 0;
      #pragma unroll
      for (int p = 0; p < 4; ++p) {
        const int cc = cp[p];
        const float v = Pvf[(q * 4 + p) * K9 + cc];
        const int ii = Pif[(q * 4 + p) * K9 + cc];
        if (v > bv || (v == bv && ii < bi)) { bv = v; bi = ii; bp = p; }
      }
      mv[r] = bv; mi[r] = bi; cp[bp]++;
    }
    const float mmax = mv[0];
    float e[K9]; float ssum = 0.f;
    #pragma unroll
    for (int r = 0; r < K9; ++r) { e[r] = expf(mv[r] - mmax); ssum += e[r]; }
    const float inv = 1.f / ssum;
    #pragma unroll
    for (int r = 0; r < K9; ++r) { Wlsf[q * K9 + r] = e[r] * inv; Ilsf[q * K9 + r] = mi[r]; }
  }
  __syncthreads();
  {
    const int q = tid >> 2, cg = tid & 3;
    float o[16];
    #pragma unroll
    for (int c = 0; c < 16; ++c) o[c] = 0.f;
    const float* vbase = vb + (size_t)(cg * 16) * NPIX;
    #pragma unroll
    for (int r = 0; r < K9; ++r) {
      const float wv = Wlsf[q * K9 + r];
      const int m = Ilsf[q * K9 + r];
      #pragma unroll
      for (int c = 0; c < 16; ++c)
        o[c] = fmaf(wv, vbase[(size_t)c * NPIX + m], o[c]);
    }
    float* op = Og + ((size_t)b * NPIX + n0 + q) * HD + cg * 16;
    #pragma unroll
    for (int c4 = 0; c4 < 4; ++c4)
      *reinterpret_cast<float4*>(op + c4 * 4) =
        make_float4(o[c4 * 4], o[c4 * 4 + 1], o[c4 * 4 + 2], o[c4 * 4 + 3]);
  }
}

// ================= launch =====================================================
extern "C" void kernel_launch(void* const* d_in, const int* in_sizes, int n_in,
                              void* d_out, int out_size, void* d_ws, size_t ws_size,
                              hipStream_t stream) {
  const float* q = (const float*)d_in[0];
  const float* k = (const float*)d_in[1];
  const float* v = (const float*)d_in[2];
  float* o = (float*)d_out;

  const size_t asz = (size_t)B4 * NPIX * HD;          // elements per split array
  const size_t need = asz * 2 * 4;                    // 4 arrays of ushort
  if (ws_size < need) {
    dim3 grid(NPIX / QT, B4);
    topk_attn_fb<<<grid, dim3(256), 0, stream>>>(q, k, v, o);
    return;
  }

  ushort_t* Qh = (ushort_t*)d_ws;
  ushort_t* Ql = Qh + asz;
  ushort_t* Kh = Ql + asz;
  ushort_t* Kl = Kh + asz;

  prep_kernel<<<dim3(NPIX / 64, B4, 2), 256, 0, stream>>>(q, k, Qh, Ql, Kh, Kl);
  attn_main<<<dim3(NQCH, B4), 256, 0, stream>>>(Qh, Ql, Kh, Kl, v, o);
}

// Round 3
// 535.435 us; speedup vs baseline: 5.0207x; 1.1363x over previous
//
#include <hip/hip_runtime.h>
#include <math.h>

#define HD   64
#define NPIX 9216
#define B4   4
#define K9   9
#define QB   32              // queries per block (main kernel)
#define NQCH (NPIX / QB)     // 288
#define KQ   (NPIX / 4)      // 2304 keys per wave
#define NT   (KQ / 16)       // 144 key subtiles per wave
#define DELTA 14.0f          // threshold margin in scaled-score units

typedef __attribute__((ext_vector_type(8))) short bf16x8;
typedef __attribute__((ext_vector_type(4))) float f32x4;
typedef unsigned short ushort_t;

struct Frags  { bf16x8 h0, h1, l0, l1; };
struct FragsH { bf16x8 h0, h1; };

__device__ __forceinline__ ushort_t f2bf(float x) {
  unsigned u = __float_as_uint(x);
  unsigned r = (u + 0x7fffu + ((u >> 16) & 1u)) >> 16;   // RNE
  return (ushort_t)r;
}
__device__ __forceinline__ float bf2f(ushort_t h) {
  return __uint_as_float(((unsigned)h) << 16);
}

// ---------------- prep: transpose [b][d][n] -> [b][n][d], split bf16 hi/lo ----
__global__ __launch_bounds__(256) void prep_kernel(
    const float* __restrict__ qg, const float* __restrict__ kg,
    ushort_t* __restrict__ Qh, ushort_t* __restrict__ Ql,
    ushort_t* __restrict__ Kh, ushort_t* __restrict__ Kl) {
  __shared__ float Ts[64][65];
  const int b = blockIdx.y, n0 = blockIdx.x * 64, z = blockIdx.z;
  const float* src = z ? kg : qg;
  ushort_t* dh = z ? Kh : Qh;
  ushort_t* dl = z ? Kl : Ql;
  const float scale = z ? 1.f : 8.f;   // fold x8 (= /SCALE) into Q
  const int tid = threadIdx.x;
  #pragma unroll
  for (int i = 0; i < 16; ++i) {
    const int idx = i * 256 + tid, c = idx >> 6, nl = idx & 63;
    Ts[c][nl] = src[((size_t)b * HD + c) * NPIX + n0 + nl];
  }
  __syncthreads();
  #pragma unroll
  for (int i = 0; i < 16; ++i) {
    const int idx = i * 256 + tid, nl = idx >> 6, d = idx & 63;
    const float x = Ts[d][nl] * scale;
    const ushort_t hi = f2bf(x);
    const ushort_t lo = f2bf(x - bf2f(hi));
    const size_t o = ((size_t)b * NPIX + n0 + nl) * HD + d;
    dh[o] = hi; dl[o] = lo;
  }
}

// ---------------- helpers ----------------
__device__ __forceinline__ Frags ldfr(const ushort_t* __restrict__ ph,
                                      const ushort_t* __restrict__ pl,
                                      int row, int lg) {
  const size_t o = (size_t)row * HD + lg * 8;
  Frags f;
  f.h0 = *reinterpret_cast<const bf16x8*>(ph + o);
  f.h1 = *reinterpret_cast<const bf16x8*>(ph + o + 32);
  f.l0 = *reinterpret_cast<const bf16x8*>(pl + o);
  f.l1 = *reinterpret_cast<const bf16x8*>(pl + o + 32);
  return f;
}
__device__ __forceinline__ FragsH ldfrH(const ushort_t* __restrict__ ph,
                                        int row, int lg) {
  const size_t o = (size_t)row * HD + lg * 8;
  FragsH f;
  f.h0 = *reinterpret_cast<const bf16x8*>(ph + o);
  f.h1 = *reinterpret_cast<const bf16x8*>(ph + o + 32);
  return f;
}

__device__ __forceinline__ void ins9(float (&tv)[K9], int (&ti)[K9], float s, int m) {
  float cv = s; int ci = m;
  #pragma unroll
  for (int r = 0; r < K9; ++r) {
    const bool c = cv > tv[r];           // strict >: earlier (lower) index wins ties
    const float hv = c ? cv : tv[r];  const float lv = c ? tv[r] : cv;
    const int   hk = c ? ci : ti[r];  const int   lk = c ? ti[r] : ci;
    tv[r] = hv; ti[r] = hk; cv = lv; ci = lk;
  }
}

// -------- main: pass A (bf16 max -> tau) + pass B (split MFMA, gated top-9) --
__global__ __launch_bounds__(256, 3) void attn_main(
    const ushort_t* __restrict__ Qh, const ushort_t* __restrict__ Ql,
    const ushort_t* __restrict__ Kh, const ushort_t* __restrict__ Kl,
    const float* __restrict__ Vg, float* __restrict__ Og) {

  __shared__ float Pv[QB][16][K9];
  __shared__ int   Pi[QB][16][K9];
  __shared__ float Wls[QB][K9];
  __shared__ int   Ils[QB][K9];
  __shared__ float Part[4][QB];
  __shared__ float TauQ[QB];

  const int tid = threadIdx.x;
  const int w = tid >> 6, l = tid & 63, lg = l >> 4, lc = l & 15;
  const int b = blockIdx.y, qbase = blockIdx.x * QB;

  // Q fragments (B operand): col = lane&15 = query, k = 8*(lane>>4)+e
  const size_t qr0 = ((size_t)b * NPIX + qbase + lc) * HD + lg * 8;
  const size_t qr1 = qr0 + (size_t)16 * HD;
  Frags qf0, qf1;
  qf0.h0 = *reinterpret_cast<const bf16x8*>(Qh + qr0);
  qf0.h1 = *reinterpret_cast<const bf16x8*>(Qh + qr0 + 32);
  qf0.l0 = *reinterpret_cast<const bf16x8*>(Ql + qr0);
  qf0.l1 = *reinterpret_cast<const bf16x8*>(Ql + qr0 + 32);
  qf1.h0 = *reinterpret_cast<const bf16x8*>(Qh + qr1);
  qf1.h1 = *reinterpret_cast<const bf16x8*>(Qh + qr1 + 32);
  qf1.l0 = *reinterpret_cast<const bf16x8*>(Ql + qr1);
  qf1.l1 = *reinterpret_cast<const bf16x8*>(Ql + qr1 + 32);

  const ushort_t* kh = Kh + (size_t)b * NPIX * HD;
  const ushort_t* kl = Kl + (size_t)b * NPIX * HD;
  const int wbase = w * KQ;

  // ================= pass A: hi*hi scores, per-query running max ============
  float mA0 = -3.4e38f, mA1 = -3.4e38f;
  {
    auto stepA = [&](const FragsH& a) {
      f32x4 acc0 = {0.f, 0.f, 0.f, 0.f};
      f32x4 acc1 = {0.f, 0.f, 0.f, 0.f};
      acc0 = __builtin_amdgcn_mfma_f32_16x16x32_bf16(a.h0, qf0.h0, acc0, 0, 0, 0);
      acc1 = __builtin_amdgcn_mfma_f32_16x16x32_bf16(a.h0, qf1.h0, acc1, 0, 0, 0);
      acc0 = __builtin_amdgcn_mfma_f32_16x16x32_bf16(a.h1, qf0.h1, acc0, 0, 0, 0);
      acc1 = __builtin_amdgcn_mfma_f32_16x16x32_bf16(a.h1, qf1.h1, acc1, 0, 0, 0);
      mA0 = fmaxf(mA0, fmaxf(fmaxf(acc0[0], acc0[1]), fmaxf(acc0[2], acc0[3])));
      mA1 = fmaxf(mA1, fmaxf(fmaxf(acc1[0], acc1[1]), fmaxf(acc1[2], acc1[3])));
    };
    FragsH fa = ldfrH(kh, wbase + lc, lg);
    for (int t = 0; t < NT; t += 2) {
      FragsH fb = ldfrH(kh, wbase + (t + 1) * 16 + lc, lg);
      stepA(fa);
      const int tn = (t + 2 < NT) ? (t + 2) : 0;
      FragsH fc = ldfrH(kh, wbase + tn * 16 + lc, lg);
      stepA(fb);
      fa = fc;
    }
  }
  // wave butterfly over lg groups (lanes ^16, ^32)
  mA0 = fmaxf(mA0, __shfl_xor(mA0, 16, 64));
  mA0 = fmaxf(mA0, __shfl_xor(mA0, 32, 64));
  mA1 = fmaxf(mA1, __shfl_xor(mA1, 16, 64));
  mA1 = fmaxf(mA1, __shfl_xor(mA1, 32, 64));
  if (lg == 0)      Part[w][lc]      = mA0;
  else if (lg == 1) Part[w][16 + lc] = mA1;
  __syncthreads();
  if (tid < QB) {
    const float v = fmaxf(fmaxf(Part[0][tid], Part[1][tid]),
                          fmaxf(Part[2][tid], Part[3][tid]));
    TauQ[tid] = v - DELTA;
  }
  __syncthreads();
  const float tau0 = TauQ[lc];
  const float tau1 = TauQ[16 + lc];

  // ================= pass B: split-precision scores, gated top-9 ============
  float tv0[K9], tv1[K9]; int ti0[K9], ti1[K9];
  #pragma unroll
  for (int r = 0; r < K9; ++r) { tv0[r] = -3.4e38f; tv1[r] = -3.4e38f; ti0[r] = 0; ti1[r] = 0; }

  auto scan4 = [&](const f32x4& s, int kb, float tau, float (&tv)[K9], int (&ti)[K9]) {
    const float m = fmaxf(fmaxf(s[0], s[1]), fmaxf(s[2], s[3]));
    if (m > fmaxf(tv[8], tau)) {
      if (s[0] > fmaxf(tv[8], tau)) ins9(tv, ti, s[0], kb);
      if (s[1] > fmaxf(tv[8], tau)) ins9(tv, ti, s[1], kb + 1);
      if (s[2] > fmaxf(tv[8], tau)) ins9(tv, ti, s[2], kb + 2);
      if (s[3] > fmaxf(tv[8], tau)) ins9(tv, ti, s[3], kb + 3);
    }
  };

  auto step = [&](const Frags& a, int key0) {
    f32x4 acc0 = {0.f, 0.f, 0.f, 0.f};
    f32x4 acc1 = {0.f, 0.f, 0.f, 0.f};
    acc0 = __builtin_amdgcn_mfma_f32_16x16x32_bf16(a.h0, qf0.h0, acc0, 0, 0, 0);
    acc1 = __builtin_amdgcn_mfma_f32_16x16x32_bf16(a.h0, qf1.h0, acc1, 0, 0, 0);
    acc0 = __builtin_amdgcn_mfma_f32_16x16x32_bf16(a.h1, qf0.h1, acc0, 0, 0, 0);
    acc1 = __builtin_amdgcn_mfma_f32_16x16x32_bf16(a.h1, qf1.h1, acc1, 0, 0, 0);
    acc0 = __builtin_amdgcn_mfma_f32_16x16x32_bf16(a.l0, qf0.h0, acc0, 0, 0, 0);
    acc1 = __builtin_amdgcn_mfma_f32_16x16x32_bf16(a.l0, qf1.h0, acc1, 0, 0, 0);
    acc0 = __builtin_amdgcn_mfma_f32_16x16x32_bf16(a.l1, qf0.h1, acc0, 0, 0, 0);
    acc1 = __builtin_amdgcn_mfma_f32_16x16x32_bf16(a.l1, qf1.h1, acc1, 0, 0, 0);
    acc0 = __builtin_amdgcn_mfma_f32_16x16x32_bf16(a.h0, qf0.l0, acc0, 0, 0, 0);
    acc1 = __builtin_amdgcn_mfma_f32_16x16x32_bf16(a.h0, qf1.l0, acc1, 0, 0, 0);
    acc0 = __builtin_amdgcn_mfma_f32_16x16x32_bf16(a.h1, qf0.l1, acc0, 0, 0, 0);
    acc1 = __builtin_amdgcn_mfma_f32_16x16x32_bf16(a.h1, qf1.l1, acc1, 0, 0, 0);
    const int kb = key0 + lg * 4;   // C/D: row = (lane>>4)*4 + reg = key offset
    scan4(acc0, kb, tau0, tv0, ti0);
    scan4(acc1, kb, tau1, tv1, ti1);
  };

  {
    Frags fa = ldfr(kh, kl, wbase + lc, lg);
    for (int t = 0; t < NT; t += 2) {
      Frags fb = ldfr(kh, kl, wbase + (t + 1) * 16 + lc, lg);
      step(fa, wbase + t * 16);
      const int tn = (t + 2 < NT) ? (t + 2) : 0;   // dummy reload at end, discarded
      Frags fc = ldfr(kh, kl, wbase + tn * 16 + lc, lg);
      step(fb, wbase + (t + 1) * 16);
      fa = fc;
    }
  }

  // ---- dump 16 partial lists per query ----
  #pragma unroll
  for (int r = 0; r < K9; ++r) {
    Pv[lc][w * 4 + lg][r] = tv0[r];  Pi[lc][w * 4 + lg][r] = ti0[r];
    Pv[16 + lc][w * 4 + lg][r] = tv1[r];  Pi[16 + lc][w * 4 + lg][r] = ti1[r];
  }
  __syncthreads();

  // ---- stage A: 128 threads, each merges 4 sorted lists -> 1 ----
  float mvA[K9]; int miA[K9];
  const int qlA = tid >> 2, quA = tid & 3;
  if (tid < 128) {
    int cp[4] = {0, 0, 0, 0};
    #pragma unroll
    for (int r = 0; r < K9; ++r) {
      float bv = -3.4e38f; int bi = 0x7fffffff, bp = 0;
      #pragma unroll
      for (int p = 0; p < 4; ++p) {
        const float v = Pv[qlA][quA * 4 + p][cp[p]];
        const int   i = Pi[qlA][quA * 4 + p][cp[p]];
        if (v > bv || (v == bv && i < bi)) { bv = v; bi = i; bp = p; }
      }
      mvA[r] = bv; miA[r] = bi; cp[bp]++;
    }
  }
  __syncthreads();
  if (tid < 128) {
    #pragma unroll
    for (int r = 0; r < K9; ++r) { Pv[qlA][quA][r] = mvA[r]; Pi[qlA][quA][r] = miA[r]; }
  }
  __syncthreads();

  // ---- stage B: 32 threads, final merge + softmax ----
  if (tid < QB) {
    const int q = tid;
    int cp[4] = {0, 0, 0, 0};
    float mv[K9]; int mi[K9];
    #pragma unroll
    for (int r = 0; r < K9; ++r) {
      float bv = -3.4e38f; int bi = 0x7fffffff, bp = 0;
      #pragma unroll
      for (int p = 0; p < 4; ++p) {
        const float v = Pv[q][p][cp[p]];
        const int   i = Pi[q][p][cp[p]];
        if (v > bv || (v == bv && i < bi)) { bv = v; bi = i; bp = p; }
      }
      mv[r] = bv; mi[r] = bi; cp[bp]++;
    }
    const float mmax = mv[0];
    float e[K9]; float ssum = 0.f;
    #pragma unroll
    for (int r = 0; r < K9; ++r) { e[r] = expf(mv[r] - mmax); ssum += e[r]; }
    const float inv = 1.f / ssum;
    #pragma unroll
    for (int r = 0; r < K9; ++r) { Wls[q][r] = e[r] * inv; Ils[q][r] = mi[r]; }
  }
  __syncthreads();

  // ---- V gather + output ----
  {
    const float* vb = Vg + (size_t)b * HD * NPIX;
    const int qloc = tid >> 3, cg = tid & 7;
    float o[8];
    #pragma unroll
    for (int c = 0; c < 8; ++c) o[c] = 0.f;
    #pragma unroll
    for (int r = 0; r < K9; ++r) {
      const float wgt = Wls[qloc][r];
      const int   m   = Ils[qloc][r];
      #pragma unroll
      for (int c = 0; c < 8; ++c)
        o[c] = fmaf(wgt, vb[(size_t)(cg * 8 + c) * NPIX + m], o[c]);
    }
    float* op = Og + (((size_t)b * NPIX) + qbase + qloc) * HD + cg * 8;
    *reinterpret_cast<float4*>(op)     = make_float4(o[0], o[1], o[2], o[3]);
    *reinterpret_cast<float4*>(op + 4) = make_float4(o[4], o[5], o[6], o[7]);
  }
}

// ================= launch =====================================================
extern "C" void kernel_launch(void* const* d_in, const int* in_sizes, int n_in,
                              void* d_out, int out_size, void* d_ws, size_t ws_size,
                              hipStream_t stream) {
  const float* q = (const float*)d_in[0];
  const float* k = (const float*)d_in[1];
  const float* v = (const float*)d_in[2];
  float* o = (float*)d_out;

  ushort_t* Qh = (ushort_t*)d_ws;
  const size_t asz = (size_t)B4 * NPIX * HD;          // elements per split array
  ushort_t* Ql = Qh + asz;
  ushort_t* Kh = Ql + asz;
  ushort_t* Kl = Kh + asz;

  prep_kernel<<<dim3(NPIX / 64, B4, 2), 256, 0, stream>>>(q, k, Qh, Ql, Kh, Kl);
  attn_main<<<dim3(NQCH, B4), 256, 0, stream>>>(Qh, Ql, Kh, Kl, v, o);
}

// Round 4
// 495.408 us; speedup vs baseline: 5.4264x; 1.0808x over previous
//
#include <hip/hip_runtime.h>
#include <math.h>

#define HD    64
#define NPIX  9216
#define B4    4
#define K9    9
#define QBLK  128            // queries per block (4 waves x 32)
#define KT    32             // keys per LDS tile
#define NTILE (NPIX / KT)    // 288
#define DELTA 14.0f

typedef __attribute__((ext_vector_type(8))) short bf16x8;
typedef __attribute__((ext_vector_type(4))) float f32x4;
typedef unsigned short ushort_t;

__device__ __forceinline__ ushort_t f2bf(float x) {
  unsigned u = __float_as_uint(x);
  unsigned r = (u + 0x7fffu + ((u >> 16) & 1u)) >> 16;   // RNE
  return (ushort_t)r;
}
__device__ __forceinline__ float bf2f(ushort_t h) {
  return __uint_as_float(((unsigned)h) << 16);
}

// ---------------- prep: transpose [b][d][n] -> [b][n][d], split bf16 hi/lo ----
__global__ __launch_bounds__(256) void prep_kernel(
    const float* __restrict__ qg, const float* __restrict__ kg,
    ushort_t* __restrict__ Qh, ushort_t* __restrict__ Ql,
    ushort_t* __restrict__ Kh, ushort_t* __restrict__ Kl) {
  __shared__ float Ts[64][65];
  const int b = blockIdx.y, n0 = blockIdx.x * 64, z = blockIdx.z;
  const float* src = z ? kg : qg;
  ushort_t* dh = z ? Kh : Qh;
  ushort_t* dl = z ? Kl : Ql;
  const float scale = z ? 1.f : 8.f;   // fold x8 (= /SCALE) into Q
  const int tid = threadIdx.x;
  #pragma unroll
  for (int i = 0; i < 16; ++i) {
    const int idx = i * 256 + tid, c = idx >> 6, nl = idx & 63;
    Ts[c][nl] = src[((size_t)b * HD + c) * NPIX + n0 + nl];
  }
  __syncthreads();
  #pragma unroll
  for (int i = 0; i < 16; ++i) {
    const int idx = i * 256 + tid, nl = idx >> 6, d = idx & 63;
    const float x = Ts[d][nl] * scale;
    const ushort_t hi = f2bf(x);
    const ushort_t lo = f2bf(x - bf2f(hi));
    const size_t o = ((size_t)b * NPIX + n0 + nl) * HD + d;
    dh[o] = hi; dl[o] = lo;
  }
}

// ---------------- async global -> LDS (16B per lane, linear dest) ------------
__device__ __forceinline__ void gl_lds16(const void* g, void* l) {
  auto gp = reinterpret_cast<const unsigned int __attribute__((address_space(1)))*>(
      reinterpret_cast<uintptr_t>(g));
  auto lp = reinterpret_cast<unsigned int __attribute__((address_space(3)))*>(
      reinterpret_cast<uintptr_t>(l));
  __builtin_amdgcn_global_load_lds(gp, lp, 16, 0, 0);
}

__device__ __forceinline__ void ins9(float (&tv)[K9], int (&ti)[K9], float s, int m) {
  float cv = s; int ci = m;
  #pragma unroll
  for (int r = 0; r < K9; ++r) {
    const bool c = cv > tv[r];           // strict >: earlier (lower) index wins ties
    const float hv = c ? cv : tv[r];  const float lv = c ? tv[r] : cv;
    const int   hk = c ? ci : ti[r];  const int   lk = c ? ti[r] : ci;
    tv[r] = hv; ti[r] = hk; cv = lv; ci = lk;
  }
}

// ---- main: shared swizzled K tiles + fused running-max tau + per-lane top-9 --
__global__ __launch_bounds__(256, 3) void attn_main(
    const ushort_t* __restrict__ Qh, const ushort_t* __restrict__ Ql,
    const ushort_t* __restrict__ Kh, const ushort_t* __restrict__ Kl,
    const float* __restrict__ Vg, float* __restrict__ Og) {

  // LDS: 16KB K-tiles (double-buffered h+l) + 36KB partial lists = 53.25KB -> 3 blocks/CU
  __shared__ __align__(16) char Kt[2][8192];        // [buf]: h at [0,4K), l at [4K,8K); 32 rows x 128B, swizzled
  __shared__ float Pv[QBLK][4][K9];
  __shared__ int   Pi[QBLK][4][K9];

  const int tid = threadIdx.x;
  const int w = tid >> 6, l = tid & 63, lg = l >> 4, lc = l & 15;
  const int b = blockIdx.y, qbase = blockIdx.x * QBLK;

  // ---- Q fragments (B operand): col = lane&15 = query, k = 8*(lane>>4)+e ----
  const int qw = qbase + w * 32;
  const size_t qr0 = ((size_t)b * NPIX + qw + lc) * HD + lg * 8;
  const size_t qr1 = qr0 + (size_t)16 * HD;
  bf16x8 q0h0 = *reinterpret_cast<const bf16x8*>(Qh + qr0);
  bf16x8 q0h1 = *reinterpret_cast<const bf16x8*>(Qh + qr0 + 32);
  bf16x8 q0l0 = *reinterpret_cast<const bf16x8*>(Ql + qr0);
  bf16x8 q0l1 = *reinterpret_cast<const bf16x8*>(Ql + qr0 + 32);
  bf16x8 q1h0 = *reinterpret_cast<const bf16x8*>(Qh + qr1);
  bf16x8 q1h1 = *reinterpret_cast<const bf16x8*>(Qh + qr1 + 32);
  bf16x8 q1l0 = *reinterpret_cast<const bf16x8*>(Ql + qr1);
  bf16x8 q1l1 = *reinterpret_cast<const bf16x8*>(Ql + qr1 + 32);

  const char* khB = reinterpret_cast<const char*>(Kh + (size_t)b * NPIX * HD);
  const char* klB = reinterpret_cast<const char*>(Kl + (size_t)b * NPIX * HD);

  // staging: lane's LDS 16B-block BL = tid (256 blocks = 4KB per array);
  // LDS block (r, c') holds global block (r, c' ^ (r&7))  [bank swizzle]
  const int sr = tid >> 3, sc = tid & 7;
  const int srcoff = sr * 128 + ((sc ^ (sr & 7)) << 4);
  const int hdst = w * 1024;                 // wave-uniform LDS byte base (h region)

  // read-side swizzled 16B-block offsets (row parity bits = lc&7 for both steps)
  const int o0 = ((lg ^ (lc & 7)) << 4);           // k-half 0 (blocks 0..3)
  const int o1 = (((4 + lg) ^ (lc & 7)) << 4);     // k-half 1 (blocks 4..7)

  auto stage = [&](int tile, int nb) {
    const size_t toff = (size_t)tile * (KT * 128) + srcoff;
    gl_lds16(khB + toff, &Kt[nb][hdst]);
    gl_lds16(klB + toff, &Kt[nb][4096 + hdst]);
  };

  float tv0[K9], tv1[K9]; int ti0[K9], ti1[K9];
  #pragma unroll
  for (int r = 0; r < K9; ++r) { tv0[r] = -3.4e38f; tv1[r] = -3.4e38f; ti0[r] = 0; ti1[r] = 0; }
  float m0 = -3.4e38f, m1 = -3.4e38f;

  stage(0, 0);
  __syncthreads();   // drains vmcnt(0) before barrier

  for (int t = 0; t < NTILE; ++t) {
    const int cur = t & 1;
    if (t + 1 < NTILE) stage(t + 1, cur ^ 1);

    #pragma unroll
    for (int s = 0; s < 2; ++s) {
      const int ro = (s * 16 + lc) * 128;
      const bf16x8 ah0 = *reinterpret_cast<const bf16x8*>(&Kt[cur][ro + o0]);
      const bf16x8 ah1 = *reinterpret_cast<const bf16x8*>(&Kt[cur][ro + o1]);
      const bf16x8 al0 = *reinterpret_cast<const bf16x8*>(&Kt[cur][4096 + ro + o0]);
      const bf16x8 al1 = *reinterpret_cast<const bf16x8*>(&Kt[cur][4096 + ro + o1]);

      f32x4 acc0 = {0.f, 0.f, 0.f, 0.f};
      f32x4 acc1 = {0.f, 0.f, 0.f, 0.f};
      acc0 = __builtin_amdgcn_mfma_f32_16x16x32_bf16(ah0, q0h0, acc0, 0, 0, 0);
      acc1 = __builtin_amdgcn_mfma_f32_16x16x32_bf16(ah0, q1h0, acc1, 0, 0, 0);
      acc0 = __builtin_amdgcn_mfma_f32_16x16x32_bf16(ah1, q0h1, acc0, 0, 0, 0);
      acc1 = __builtin_amdgcn_mfma_f32_16x16x32_bf16(ah1, q1h1, acc1, 0, 0, 0);
      acc0 = __builtin_amdgcn_mfma_f32_16x16x32_bf16(al0, q0h0, acc0, 0, 0, 0);
      acc1 = __builtin_amdgcn_mfma_f32_16x16x32_bf16(al0, q1h0, acc1, 0, 0, 0);
      acc0 = __builtin_amdgcn_mfma_f32_16x16x32_bf16(al1, q0h1, acc0, 0, 0, 0);
      acc1 = __builtin_amdgcn_mfma_f32_16x16x32_bf16(al1, q1h1, acc1, 0, 0, 0);
      acc0 = __builtin_amdgcn_mfma_f32_16x16x32_bf16(ah0, q0l0, acc0, 0, 0, 0);
      acc1 = __builtin_amdgcn_mfma_f32_16x16x32_bf16(ah0, q1l0, acc1, 0, 0, 0);
      acc0 = __builtin_amdgcn_mfma_f32_16x16x32_bf16(ah1, q0l1, acc0, 0, 0, 0);
      acc1 = __builtin_amdgcn_mfma_f32_16x16x32_bf16(ah1, q1l1, acc1, 0, 0, 0);

      // running per-query max (combine the 4 key-lanes of each query column)
      float s40 = fmaxf(fmaxf(acc0[0], acc0[1]), fmaxf(acc0[2], acc0[3]));
      float s41 = fmaxf(fmaxf(acc1[0], acc1[1]), fmaxf(acc1[2], acc1[3]));
      float g0 = fmaxf(s40, __shfl_xor(s40, 16, 64));
      g0 = fmaxf(g0, __shfl_xor(g0, 32, 64));
      float g1 = fmaxf(s41, __shfl_xor(s41, 16, 64));
      g1 = fmaxf(g1, __shfl_xor(g1, 32, 64));
      m0 = fmaxf(m0, g0);
      m1 = fmaxf(m1, g1);

      const int kb = t * KT + s * 16 + lg * 4;   // C/D: row = (lane>>4)*4 + reg
      const float gate0 = fmaxf(tv0[8], m0 - DELTA);
      if (s40 > gate0) {
        if (acc0[0] > gate0) ins9(tv0, ti0, acc0[0], kb);
        if (acc0[1] > gate0) ins9(tv0, ti0, acc0[1], kb + 1);
        if (acc0[2] > gate0) ins9(tv0, ti0, acc0[2], kb + 2);
        if (acc0[3] > gate0) ins9(tv0, ti0, acc0[3], kb + 3);
      }
      const float gate1 = fmaxf(tv1[8], m1 - DELTA);
      if (s41 > gate1) {
        if (acc1[0] > gate1) ins9(tv1, ti1, acc1[0], kb);
        if (acc1[1] > gate1) ins9(tv1, ti1, acc1[1], kb + 1);
        if (acc1[2] > gate1) ins9(tv1, ti1, acc1[2], kb + 2);
        if (acc1[3] > gate1) ins9(tv1, ti1, acc1[3], kb + 3);
      }
    }
    __syncthreads();   // drains stage vmcnt + protects buf flip
  }

  // ---- dump 4 partial lists per query ----
  {
    const int ql0 = w * 32 + lc, ql1 = ql0 + 16;
    #pragma unroll
    for (int r = 0; r < K9; ++r) {
      Pv[ql0][lg][r] = tv0[r];  Pi[ql0][lg][r] = ti0[r];
      Pv[ql1][lg][r] = tv1[r];  Pi[ql1][lg][r] = ti1[r];
    }
  }
  __syncthreads();

  // ---- merge + softmax (one thread per query); Wls/Ils overlay the K tiles --
  float* Wls = reinterpret_cast<float*>(&Kt[0][0]);          // [QBLK][K9]
  int*   Ils = reinterpret_cast<int*>(&Kt[0][0]) + QBLK * K9;
  if (tid < QBLK) {
    const int q = tid;
    int cp[4] = {0, 0, 0, 0};
    float mv[K9]; int mi[K9];
    #pragma unroll
    for (int r = 0; r < K9; ++r) {
      float bv = -3.4e38f; int bi = 0x7fffffff, bp = 0;
      #pragma unroll
      for (int p = 0; p < 4; ++p) {
        const float v = Pv[q][p][cp[p]];
        const int   i = Pi[q][p][cp[p]];
        if (v > bv || (v == bv && i < bi)) { bv = v; bi = i; bp = p; }
      }
      mv[r] = bv; mi[r] = bi; cp[bp]++;
    }
    const float mmax = mv[0];
    float e[K9]; float ssum = 0.f;
    #pragma unroll
    for (int r = 0; r < K9; ++r) { e[r] = expf(mv[r] - mmax); ssum += e[r]; }
    const float inv = 1.f / ssum;
    #pragma unroll
    for (int r = 0; r < K9; ++r) { Wls[q * K9 + r] = e[r] * inv; Ils[q * K9 + r] = mi[r]; }
  }
  __syncthreads();

  // ---- V gather + output (2 threads per query, 32 dims each) ----
  {
    const float* vb = Vg + (size_t)b * HD * NPIX;
    const int q = tid >> 1, dh2 = (tid & 1) * 32;
    float o[32];
    #pragma unroll
    for (int c = 0; c < 32; ++c) o[c] = 0.f;
    #pragma unroll
    for (int r = 0; r < K9; ++r) {
      const float wgt = Wls[q * K9 + r];
      const int   m   = Ils[q * K9 + r];
      const float* vcol = vb + (size_t)dh2 * NPIX + m;
      #pragma unroll
      for (int c = 0; c < 32; ++c)
        o[c] = fmaf(wgt, vcol[(size_t)c * NPIX], o[c]);
    }
    float* op = Og + (((size_t)b * NPIX) + qbase + q) * HD + dh2;
    #pragma unroll
    for (int c4 = 0; c4 < 8; ++c4)
      *reinterpret_cast<float4*>(op + c4 * 4) =
        make_float4(o[c4 * 4], o[c4 * 4 + 1], o[c4 * 4 + 2], o[c4 * 4 + 3]);
  }
}

// ================= launch =====================================================
extern "C" void kernel_launch(void* const* d_in, const int* in_sizes, int n_in,
                              void* d_out, int out_size, void* d_ws, size_t ws_size,
                              hipStream_t stream) {
  const float* q = (const float*)d_in[0];
  const float* k = (const float*)d_in[1];
  const float* v = (const float*)d_in[2];
  float* o = (float*)d_out;

  ushort_t* Qh = (ushort_t*)d_ws;
  const size_t asz = (size_t)B4 * NPIX * HD;          // elements per split array
  ushort_t* Ql = Qh + asz;
  ushort_t* Kh = Ql + asz;
  ushort_t* Kl = Kh + asz;

  prep_kernel<<<dim3(NPIX / 64, B4, 2), 256, 0, stream>>>(q, k, Qh, Ql, Kh, Kl);
  attn_main<<<dim3(NPIX / QBLK, B4), 256, 0, stream>>>(Qh, Ql, Kh, Kl, v, o);
}

// Round 5
// 339.659 us; speedup vs baseline: 7.9146x; 1.4585x over previous
//
#include <hip/hip_runtime.h>
#include <math.h>

#define HD    64
#define NPIX  9216
#define B4    4
#define K9    9
#define QBLK  128            // queries per block (4 waves x 32)
#define KT    32             // keys per LDS tile
#define KQZ   (NPIX / 4)     // 2304 keys per block (one quarter)
#define NTZ   (KQZ / KT)     // 72 tiles
#define DELTA 14.0f

typedef __attribute__((ext_vector_type(8))) short bf16x8;
typedef __attribute__((ext_vector_type(4))) float f32x4;
typedef unsigned short ushort_t;

__device__ __forceinline__ ushort_t f2bf(float x) {
  unsigned u = __float_as_uint(x);
  unsigned r = (u + 0x7fffu + ((u >> 16) & 1u)) >> 16;   // RNE
  return (ushort_t)r;
}
__device__ __forceinline__ float bf2f(ushort_t h) {
  return __uint_as_float(((unsigned)h) << 16);
}

// ---- prep: transpose [b][d][n] -> [b][n][d]; z<2: bf16 hi/lo split; z==2: V fp32
__global__ __launch_bounds__(256) void prep_kernel(
    const float* __restrict__ qg, const float* __restrict__ kg,
    const float* __restrict__ vg,
    ushort_t* __restrict__ Qh, ushort_t* __restrict__ Ql,
    ushort_t* __restrict__ Kh, ushort_t* __restrict__ Kl,
    float* __restrict__ Vt) {
  __shared__ float Ts[64][65];
  const int b = blockIdx.y, n0 = blockIdx.x * 64, z = blockIdx.z;
  const float* src = (z == 0) ? qg : (z == 1) ? kg : vg;
  const float scale = (z == 0) ? 8.f : 1.f;   // fold x8 (= /SCALE) into Q
  const int tid = threadIdx.x;
  #pragma unroll
  for (int i = 0; i < 16; ++i) {
    const int idx = i * 256 + tid, c = idx >> 6, nl = idx & 63;
    Ts[c][nl] = src[((size_t)b * HD + c) * NPIX + n0 + nl];
  }
  __syncthreads();
  if (z < 2) {
    ushort_t* dh = z ? Kh : Qh;
    ushort_t* dl = z ? Kl : Ql;
    #pragma unroll
    for (int i = 0; i < 16; ++i) {
      const int idx = i * 256 + tid, nl = idx >> 6, d = idx & 63;
      const float x = Ts[d][nl] * scale;
      const ushort_t hi = f2bf(x);
      const ushort_t lo = f2bf(x - bf2f(hi));
      const size_t o = ((size_t)b * NPIX + n0 + nl) * HD + d;
      dh[o] = hi; dl[o] = lo;
    }
  } else {
    #pragma unroll
    for (int i = 0; i < 16; ++i) {
      const int idx = i * 256 + tid, nl = idx >> 6, d = idx & 63;
      Vt[((size_t)b * NPIX + n0 + nl) * HD + d] = Ts[d][nl];
    }
  }
}

// ---------------- async global -> LDS (16B per lane, linear dest) ------------
__device__ __forceinline__ void gl_lds16(const void* g, void* l) {
  auto gp = reinterpret_cast<const unsigned int __attribute__((address_space(1)))*>(
      reinterpret_cast<uintptr_t>(g));
  auto lp = reinterpret_cast<unsigned int __attribute__((address_space(3)))*>(
      reinterpret_cast<uintptr_t>(l));
  __builtin_amdgcn_global_load_lds(gp, lp, 16, 0, 0);
}

__device__ __forceinline__ void ins9(float (&tv)[K9], int (&ti)[K9], float s, int m) {
  float cv = s; int ci = m;
  #pragma unroll
  for (int r = 0; r < K9; ++r) {
    const bool c = cv > tv[r];           // strict >: earlier (lower) index wins ties
    const float hv = c ? cv : tv[r];  const float lv = c ? tv[r] : cv;
    const int   hk = c ? ci : ti[r];  const int   lk = c ? ti[r] : ci;
    tv[r] = hv; ti[r] = hk; cv = lv; ci = lk;
  }
}

// ---- main: one key-quarter per block; swizzled shared K tiles; per-lane top-9
__global__ __launch_bounds__(256, 4) void attn_main(
    const ushort_t* __restrict__ Qh, const ushort_t* __restrict__ Ql,
    const ushort_t* __restrict__ Kh, const ushort_t* __restrict__ Kl,
    float2* __restrict__ Lout) {

  // 36 KB shared, overlaid: [0,16K) = K-tile double buffer during the loop;
  // after the loop the whole region becomes the partial-list arrays.
  __shared__ __align__(16) char SMEM[36864];
  float (*Pv)[4][K9] = reinterpret_cast<float (*)[4][K9]>(SMEM);          // [128][4][9]
  int   (*Pi)[4][K9] = reinterpret_cast<int (*)[4][K9]>(SMEM + 18432);

  const int tid = threadIdx.x;
  const int w = tid >> 6, l = tid & 63, lg = l >> 4, lc = l & 15;
  const int b = blockIdx.y, qbase = blockIdx.x * QBLK, z = blockIdx.z;
  const int kbase = z * KQZ;

  // ---- Q fragments (B operand): col = lane&15 = query, k = 8*(lane>>4)+e ----
  const int qw = qbase + w * 32;
  const size_t qr0 = ((size_t)b * NPIX + qw + lc) * HD + lg * 8;
  const size_t qr1 = qr0 + (size_t)16 * HD;
  const bf16x8 q0h0 = *reinterpret_cast<const bf16x8*>(Qh + qr0);
  const bf16x8 q0h1 = *reinterpret_cast<const bf16x8*>(Qh + qr0 + 32);
  const bf16x8 q0l0 = *reinterpret_cast<const bf16x8*>(Ql + qr0);
  const bf16x8 q0l1 = *reinterpret_cast<const bf16x8*>(Ql + qr0 + 32);
  const bf16x8 q1h0 = *reinterpret_cast<const bf16x8*>(Qh + qr1);
  const bf16x8 q1h1 = *reinterpret_cast<const bf16x8*>(Qh + qr1 + 32);
  const bf16x8 q1l0 = *reinterpret_cast<const bf16x8*>(Ql + qr1);
  const bf16x8 q1l1 = *reinterpret_cast<const bf16x8*>(Ql + qr1 + 32);

  const char* khB = reinterpret_cast<const char*>(Kh + (size_t)b * NPIX * HD);
  const char* klB = reinterpret_cast<const char*>(Kl + (size_t)b * NPIX * HD);

  // staging: lane's LDS 16B-block = tid; LDS block (r,c') holds global (r, c'^(r&7))
  const int sr = tid >> 3, sc = tid & 7;
  const int srcoff = sr * 128 + ((sc ^ (sr & 7)) << 4);
  const int hdst = w * 1024;                 // wave-uniform LDS byte base (h region)

  // read-side swizzled 16B-block offsets
  const int o0 = ((lg ^ (lc & 7)) << 4);           // k-half 0
  const int o1 = (((4 + lg) ^ (lc & 7)) << 4);     // k-half 1

  auto stage = [&](int tile, int nb) {
    const size_t toff = ((size_t)(kbase + tile * KT)) * 128 + srcoff;
    gl_lds16(khB + toff, SMEM + nb * 8192 + hdst);
    gl_lds16(klB + toff, SMEM + nb * 8192 + 4096 + hdst);
  };

  float tv0[K9], tv1[K9]; int ti0[K9], ti1[K9];
  #pragma unroll
  for (int r = 0; r < K9; ++r) { tv0[r] = -3.4e38f; tv1[r] = -3.4e38f; ti0[r] = 0; ti1[r] = 0; }
  float m0 = -3.4e38f, m1 = -3.4e38f;

  stage(0, 0);
  __syncthreads();   // drains vmcnt(0) before barrier

  for (int t = 0; t < NTZ; ++t) {
    const int cur = t & 1;
    if (t + 1 < NTZ) stage(t + 1, cur ^ 1);
    const char* kt = SMEM + cur * 8192;

    #pragma unroll
    for (int s = 0; s < 2; ++s) {
      const int ro = (s * 16 + lc) * 128;
      const bf16x8 ah0 = *reinterpret_cast<const bf16x8*>(kt + ro + o0);
      const bf16x8 ah1 = *reinterpret_cast<const bf16x8*>(kt + ro + o1);
      const bf16x8 al0 = *reinterpret_cast<const bf16x8*>(kt + 4096 + ro + o0);
      const bf16x8 al1 = *reinterpret_cast<const bf16x8*>(kt + 4096 + ro + o1);

      f32x4 acc0 = {0.f, 0.f, 0.f, 0.f};
      f32x4 acc1 = {0.f, 0.f, 0.f, 0.f};
      acc0 = __builtin_amdgcn_mfma_f32_16x16x32_bf16(ah0, q0h0, acc0, 0, 0, 0);
      acc1 = __builtin_amdgcn_mfma_f32_16x16x32_bf16(ah0, q1h0, acc1, 0, 0, 0);
      acc0 = __builtin_amdgcn_mfma_f32_16x16x32_bf16(ah1, q0h1, acc0, 0, 0, 0);
      acc1 = __builtin_amdgcn_mfma_f32_16x16x32_bf16(ah1, q1h1, acc1, 0, 0, 0);
      acc0 = __builtin_amdgcn_mfma_f32_16x16x32_bf16(al0, q0h0, acc0, 0, 0, 0);
      acc1 = __builtin_amdgcn_mfma_f32_16x16x32_bf16(al0, q1h0, acc1, 0, 0, 0);
      acc0 = __builtin_amdgcn_mfma_f32_16x16x32_bf16(al1, q0h1, acc0, 0, 0, 0);
      acc1 = __builtin_amdgcn_mfma_f32_16x16x32_bf16(al1, q1h1, acc1, 0, 0, 0);
      acc0 = __builtin_amdgcn_mfma_f32_16x16x32_bf16(ah0, q0l0, acc0, 0, 0, 0);
      acc1 = __builtin_amdgcn_mfma_f32_16x16x32_bf16(ah0, q1l0, acc1, 0, 0, 0);
      acc0 = __builtin_amdgcn_mfma_f32_16x16x32_bf16(ah1, q0l1, acc0, 0, 0, 0);
      acc1 = __builtin_amdgcn_mfma_f32_16x16x32_bf16(ah1, q1l1, acc1, 0, 0, 0);

      // running per-query max across the 4 key-lane groups
      float s40 = fmaxf(fmaxf(acc0[0], acc0[1]), fmaxf(acc0[2], acc0[3]));
      float s41 = fmaxf(fmaxf(acc1[0], acc1[1]), fmaxf(acc1[2], acc1[3]));
      float g0 = fmaxf(s40, __shfl_xor(s40, 16, 64));
      g0 = fmaxf(g0, __shfl_xor(g0, 32, 64));
      float g1 = fmaxf(s41, __shfl_xor(s41, 16, 64));
      g1 = fmaxf(g1, __shfl_xor(g1, 32, 64));
      m0 = fmaxf(m0, g0);
      m1 = fmaxf(m1, g1);

      const int kb = kbase + t * KT + s * 16 + lg * 4;   // C/D: row = (lane>>4)*4 + reg
      const float gate0 = fmaxf(tv0[8], m0 - DELTA);
      if (s40 > gate0) {
        if (acc0[0] > gate0) ins9(tv0, ti0, acc0[0], kb);
        if (acc0[1] > gate0) ins9(tv0, ti0, acc0[1], kb + 1);
        if (acc0[2] > gate0) ins9(tv0, ti0, acc0[2], kb + 2);
        if (acc0[3] > gate0) ins9(tv0, ti0, acc0[3], kb + 3);
      }
      const float gate1 = fmaxf(tv1[8], m1 - DELTA);
      if (s41 > gate1) {
        if (acc1[0] > gate1) ins9(tv1, ti1, acc1[0], kb);
        if (acc1[1] > gate1) ins9(tv1, ti1, acc1[1], kb + 1);
        if (acc1[2] > gate1) ins9(tv1, ti1, acc1[2], kb + 2);
        if (acc1[3] > gate1) ins9(tv1, ti1, acc1[3], kb + 3);
      }
    }
    __syncthreads();   // drains stage vmcnt + protects buf flip
  }

  // ---- dump 4 lane-group partial lists per query (SMEM now free) ----
  {
    const int ql0 = w * 32 + lc, ql1 = ql0 + 16;
    #pragma unroll
    for (int r = 0; r < K9; ++r) {
      Pv[ql0][lg][r] = tv0[r];  Pi[ql0][lg][r] = ti0[r];
      Pv[ql1][lg][r] = tv1[r];  Pi[ql1][lg][r] = ti1[r];
    }
  }
  __syncthreads();

  // ---- merge 4 lane-group lists -> one per (query, quarter), write to ws ----
  if (tid < QBLK) {
    const int q = tid;
    int cp[4] = {0, 0, 0, 0};
    float2* lp = Lout + (((size_t)b * NPIX + qbase + q) * 4 + z) * K9;
    #pragma unroll
    for (int r = 0; r < K9; ++r) {
      float bv = -3.4e38f; int bi = 0x7fffffff, bp = 0;
      #pragma unroll
      for (int p = 0; p < 4; ++p) {
        const float v = Pv[q][p][cp[p]];
        const int   i = Pi[q][p][cp[p]];
        if (v > bv || (v == bv && i < bi)) { bv = v; bi = i; bp = p; }
      }
      lp[r] = make_float2(bv, __int_as_float(bi));
      cp[bp]++;
    }
  }
}

// ---- merge quarters + softmax + V gather ------------------------------------
__global__ __launch_bounds__(256, 4) void merge_v(
    const float2* __restrict__ L, const float* __restrict__ Vt,
    float* __restrict__ Og) {
  __shared__ float Wls[128][K9];
  __shared__ int   Ils[128][K9];
  const int tid = threadIdx.x, b = blockIdx.y, qbase = blockIdx.x * 128;

  if (tid < 128) {
    const float2* base = L + ((size_t)b * NPIX + qbase + tid) * 4 * K9;
    int cp[4] = {0, 0, 0, 0};
    float mv[K9]; int mi[K9];
    #pragma unroll
    for (int r = 0; r < K9; ++r) {
      float bv = -3.4e38f; int bi = 0x7fffffff, bp = 0;
      #pragma unroll
      for (int p = 0; p < 4; ++p) {
        const float2 e = base[p * K9 + cp[p]];
        const int i = __float_as_int(e.y);
        if (e.x > bv || (e.x == bv && i < bi)) { bv = e.x; bi = i; bp = p; }
      }
      mv[r] = bv; mi[r] = bi; cp[bp]++;
    }
    const float mmax = mv[0];
    float e[K9]; float ssum = 0.f;
    #pragma unroll
    for (int r = 0; r < K9; ++r) { e[r] = expf(mv[r] - mmax); ssum += e[r]; }
    const float inv = 1.f / ssum;
    #pragma unroll
    for (int r = 0; r < K9; ++r) { Wls[tid][r] = e[r] * inv; Ils[tid][r] = mi[r]; }
  }
  __syncthreads();

  // 2 threads per query, 32 dims each; Vt rows are contiguous 256 B
  {
    const int q = tid >> 1, half = tid & 1;
    float o[32];
    #pragma unroll
    for (int c = 0; c < 32; ++c) o[c] = 0.f;
    #pragma unroll
    for (int r = 0; r < K9; ++r) {
      const float wgt = Wls[q][r];
      const int   m   = Ils[q][r];
      const float4* vp = reinterpret_cast<const float4*>(
          Vt + ((size_t)b * NPIX + m) * HD + half * 32);
      #pragma unroll
      for (int c4 = 0; c4 < 8; ++c4) {
        const float4 vv = vp[c4];
        o[c4 * 4]     = fmaf(wgt, vv.x, o[c4 * 4]);
        o[c4 * 4 + 1] = fmaf(wgt, vv.y, o[c4 * 4 + 1]);
        o[c4 * 4 + 2] = fmaf(wgt, vv.z, o[c4 * 4 + 2]);
        o[c4 * 4 + 3] = fmaf(wgt, vv.w, o[c4 * 4 + 3]);
      }
    }
    float* op = Og + (((size_t)b * NPIX) + qbase + q) * HD + half * 32;
    #pragma unroll
    for (int c4 = 0; c4 < 8; ++c4)
      *reinterpret_cast<float4*>(op + c4 * 4) =
        make_float4(o[c4 * 4], o[c4 * 4 + 1], o[c4 * 4 + 2], o[c4 * 4 + 3]);
  }
}

// ================= launch =====================================================
extern "C" void kernel_launch(void* const* d_in, const int* in_sizes, int n_in,
                              void* d_out, int out_size, void* d_ws, size_t ws_size,
                              hipStream_t stream) {
  const float* q = (const float*)d_in[0];
  const float* k = (const float*)d_in[1];
  const float* v = (const float*)d_in[2];
  float* o = (float*)d_out;

  const size_t asz = (size_t)B4 * NPIX * HD;          // 2.36M elements
  ushort_t* Qh = (ushort_t*)d_ws;
  ushort_t* Ql = Qh + asz;
  ushort_t* Kh = Ql + asz;
  ushort_t* Kl = Kh + asz;
  float*    Vt = (float*)(Kl + asz);                  // fp32 [b][n][d]
  float2*   Ls = (float2*)(Vt + asz);                 // [b][n][4][9]

  prep_kernel<<<dim3(NPIX / 64, B4, 3), 256, 0, stream>>>(q, k, v, Qh, Ql, Kh, Kl, Vt);
  attn_main<<<dim3(NPIX / QBLK, B4, 4), 256, 0, stream>>>(Qh, Ql, Kh, Kl, Ls);
  merge_v<<<dim3(NPIX / 128, B4), 256, 0, stream>>>(Ls, Vt, o);
}

// Round 6
// 199.321 us; speedup vs baseline: 13.4871x; 1.7041x over previous
//
#include <hip/hip_runtime.h>
#include <math.h>

#define HD    64
#define NPIX  9216
#define B4    4
#define K9    9
#define QBLK  128            // queries per block (4 waves x 32)
#define KT    32             // keys per LDS tile
#define KQZ   (NPIX / 4)     // 2304 keys per block (one quarter)
#define NTZ   (KQZ / KT)     // 72 tiles
#define DELTA 14.0f
#define CAP   32             // candidate buffer entries per query

typedef __attribute__((ext_vector_type(8))) short bf16x8;
typedef __attribute__((ext_vector_type(4))) float f32x4;
typedef unsigned short ushort_t;

__device__ __forceinline__ ushort_t f2bf(float x) {
  unsigned u = __float_as_uint(x);
  unsigned r = (u + 0x7fffu + ((u >> 16) & 1u)) >> 16;   // RNE
  return (ushort_t)r;
}
__device__ __forceinline__ float bf2f(ushort_t h) {
  return __uint_as_float(((unsigned)h) << 16);
}

// ---- zero candidate counters (ws is not re-poisoned between replays) --------
__global__ __launch_bounds__(256) void zero_cnt(int* __restrict__ c, int n) {
  const int i = blockIdx.x * 256 + threadIdx.x;
  if (i < n) c[i] = 0;
}

// ---- prep: transpose [b][d][n] -> [b][n][d]; z<2: bf16 hi/lo split; z==2: V fp32
__global__ __launch_bounds__(256) void prep_kernel(
    const float* __restrict__ qg, const float* __restrict__ kg,
    const float* __restrict__ vg,
    ushort_t* __restrict__ Qh, ushort_t* __restrict__ Ql,
    ushort_t* __restrict__ Kh, ushort_t* __restrict__ Kl,
    float* __restrict__ Vt) {
  __shared__ float Ts[64][65];
  const int b = blockIdx.y, n0 = blockIdx.x * 64, z = blockIdx.z;
  const float* src = (z == 0) ? qg : (z == 1) ? kg : vg;
  const float scale = (z == 0) ? 8.f : 1.f;   // fold x8 (= /SCALE) into Q
  const int tid = threadIdx.x;
  #pragma unroll
  for (int i = 0; i < 16; ++i) {
    const int idx = i * 256 + tid, c = idx >> 6, nl = idx & 63;
    Ts[c][nl] = src[((size_t)b * HD + c) * NPIX + n0 + nl];
  }
  __syncthreads();
  if (z < 2) {
    ushort_t* dh = z ? Kh : Qh;
    ushort_t* dl = z ? Kl : Ql;
    #pragma unroll
    for (int i = 0; i < 16; ++i) {
      const int idx = i * 256 + tid, nl = idx >> 6, d = idx & 63;
      const float x = Ts[d][nl] * scale;
      const ushort_t hi = f2bf(x);
      const ushort_t lo = f2bf(x - bf2f(hi));
      const size_t o = ((size_t)b * NPIX + n0 + nl) * HD + d;
      dh[o] = hi; dl[o] = lo;
    }
  } else {
    #pragma unroll
    for (int i = 0; i < 16; ++i) {
      const int idx = i * 256 + tid, nl = idx >> 6, d = idx & 63;
      Vt[((size_t)b * NPIX + n0 + nl) * HD + d] = Ts[d][nl];
    }
  }
}

// ---------------- async global -> LDS (16B per lane, linear dest) ------------
__device__ __forceinline__ void gl_lds16(const void* g, void* l) {
  auto gp = reinterpret_cast<const unsigned int __attribute__((address_space(1)))*>(
      reinterpret_cast<uintptr_t>(g));
  auto lp = reinterpret_cast<unsigned int __attribute__((address_space(3)))*>(
      reinterpret_cast<uintptr_t>(l));
  __builtin_amdgcn_global_load_lds(gp, lp, 16, 0, 0);
}

// ============ pass A: hi-only scores -> per-(query, quarter) max =============
__global__ __launch_bounds__(256, 8) void pass_max(
    const ushort_t* __restrict__ Qh, const ushort_t* __restrict__ Kh,
    float* __restrict__ Pmax) {
  __shared__ __align__(16) char SM[2][4096];   // hi-only tile, double buffered

  const int tid = threadIdx.x;
  const int w = tid >> 6, l = tid & 63, lg = l >> 4, lc = l & 15;
  const int b = blockIdx.y, qbase = blockIdx.x * QBLK, z = blockIdx.z;
  const int kbase = z * KQZ;

  const int qw = qbase + w * 32;
  const size_t qr0 = ((size_t)b * NPIX + qw + lc) * HD + lg * 8;
  const size_t qr1 = qr0 + (size_t)16 * HD;
  const bf16x8 q0h0 = *reinterpret_cast<const bf16x8*>(Qh + qr0);
  const bf16x8 q0h1 = *reinterpret_cast<const bf16x8*>(Qh + qr0 + 32);
  const bf16x8 q1h0 = *reinterpret_cast<const bf16x8*>(Qh + qr1);
  const bf16x8 q1h1 = *reinterpret_cast<const bf16x8*>(Qh + qr1 + 32);

  const char* khB = reinterpret_cast<const char*>(Kh + (size_t)b * NPIX * HD);

  const int sr = tid >> 3, sc = tid & 7;
  const int srcoff = sr * 128 + ((sc ^ (sr & 7)) << 4);
  const int hdst = w * 1024;
  const int o0 = ((lg ^ (lc & 7)) << 4);
  const int o1 = (((4 + lg) ^ (lc & 7)) << 4);

  auto stage = [&](int tile, int nb) {
    const size_t toff = ((size_t)(kbase + tile * KT)) * 128 + srcoff;
    gl_lds16(khB + toff, SM[nb] + hdst);
  };

  float m0 = -3.4e38f, m1 = -3.4e38f;
  stage(0, 0);
  __syncthreads();

  for (int t = 0; t < NTZ; ++t) {
    const int cur = t & 1;
    if (t + 1 < NTZ) stage(t + 1, cur ^ 1);
    const char* kt = SM[cur];
    #pragma unroll
    for (int s = 0; s < 2; ++s) {
      const int ro = (s * 16 + lc) * 128;
      const bf16x8 ah0 = *reinterpret_cast<const bf16x8*>(kt + ro + o0);
      const bf16x8 ah1 = *reinterpret_cast<const bf16x8*>(kt + ro + o1);
      f32x4 acc0 = {0.f, 0.f, 0.f, 0.f};
      f32x4 acc1 = {0.f, 0.f, 0.f, 0.f};
      acc0 = __builtin_amdgcn_mfma_f32_16x16x32_bf16(ah0, q0h0, acc0, 0, 0, 0);
      acc1 = __builtin_amdgcn_mfma_f32_16x16x32_bf16(ah0, q1h0, acc1, 0, 0, 0);
      acc0 = __builtin_amdgcn_mfma_f32_16x16x32_bf16(ah1, q0h1, acc0, 0, 0, 0);
      acc1 = __builtin_amdgcn_mfma_f32_16x16x32_bf16(ah1, q1h1, acc1, 0, 0, 0);
      m0 = fmaxf(m0, fmaxf(fmaxf(acc0[0], acc0[1]), fmaxf(acc0[2], acc0[3])));
      m1 = fmaxf(m1, fmaxf(fmaxf(acc1[0], acc1[1]), fmaxf(acc1[2], acc1[3])));
    }
    __syncthreads();
  }

  // cross-lane reduce over the 4 key-lane groups (lanes ^16, ^32)
  m0 = fmaxf(m0, __shfl_xor(m0, 16, 64));
  m0 = fmaxf(m0, __shfl_xor(m0, 32, 64));
  m1 = fmaxf(m1, __shfl_xor(m1, 16, 64));
  m1 = fmaxf(m1, __shfl_xor(m1, 32, 64));
  if (lg == 0) {
    Pmax[((size_t)b * NPIX + qw + lc) * 4 + z]      = m0;
    Pmax[((size_t)b * NPIX + qw + 16 + lc) * 4 + z] = m1;
  }
}

// ====== pass B: full-precision scores, tau gate, append candidates ===========
__global__ __launch_bounds__(256, 6) void pass_cand(
    const ushort_t* __restrict__ Qh, const ushort_t* __restrict__ Ql,
    const ushort_t* __restrict__ Kh, const ushort_t* __restrict__ Kl,
    const float* __restrict__ Pmax,
    int* __restrict__ Cnt, float2* __restrict__ Cand) {

  __shared__ __align__(16) char SMEM[2][8192];   // h at [0,4K), l at [4K,8K)

  const int tid = threadIdx.x;
  const int w = tid >> 6, l = tid & 63, lg = l >> 4, lc = l & 15;
  const int b = blockIdx.y, qbase = blockIdx.x * QBLK, z = blockIdx.z;
  const int kbase = z * KQZ;

  const int qw = qbase + w * 32;
  const int q0g = qw + lc, q1g = qw + 16 + lc;
  const size_t qr0 = ((size_t)b * NPIX + q0g) * HD + lg * 8;
  const size_t qr1 = ((size_t)b * NPIX + q1g) * HD + lg * 8;
  const bf16x8 q0h0 = *reinterpret_cast<const bf16x8*>(Qh + qr0);
  const bf16x8 q0h1 = *reinterpret_cast<const bf16x8*>(Qh + qr0 + 32);
  const bf16x8 q0l0 = *reinterpret_cast<const bf16x8*>(Ql + qr0);
  const bf16x8 q0l1 = *reinterpret_cast<const bf16x8*>(Ql + qr0 + 32);
  const bf16x8 q1h0 = *reinterpret_cast<const bf16x8*>(Qh + qr1);
  const bf16x8 q1h1 = *reinterpret_cast<const bf16x8*>(Qh + qr1 + 32);
  const bf16x8 q1l0 = *reinterpret_cast<const bf16x8*>(Ql + qr1);
  const bf16x8 q1l1 = *reinterpret_cast<const bf16x8*>(Ql + qr1 + 32);

  // per-query tau from global (4-quarter) hi-only max
  const float* pm0 = Pmax + ((size_t)b * NPIX + q0g) * 4;
  const float* pm1 = Pmax + ((size_t)b * NPIX + q1g) * 4;
  const float tau0 = fmaxf(fmaxf(pm0[0], pm0[1]), fmaxf(pm0[2], pm0[3])) - DELTA;
  const float tau1 = fmaxf(fmaxf(pm1[0], pm1[1]), fmaxf(pm1[2], pm1[3])) - DELTA;

  const char* khB = reinterpret_cast<const char*>(Kh + (size_t)b * NPIX * HD);
  const char* klB = reinterpret_cast<const char*>(Kl + (size_t)b * NPIX * HD);

  const int sr = tid >> 3, sc = tid & 7;
  const int srcoff = sr * 128 + ((sc ^ (sr & 7)) << 4);
  const int hdst = w * 1024;
  const int o0 = ((lg ^ (lc & 7)) << 4);
  const int o1 = (((4 + lg) ^ (lc & 7)) << 4);

  auto stage = [&](int tile, int nb) {
    const size_t toff = ((size_t)(kbase + tile * KT)) * 128 + srcoff;
    gl_lds16(khB + toff, SMEM[nb] + hdst);
    gl_lds16(klB + toff, SMEM[nb] + 4096 + hdst);
  };

  auto emit = [&](float s, int m, int qg) {
    const int qi = b * NPIX + qg;
    const int slot = atomicAdd(&Cnt[qi], 1);
    if (slot < CAP) Cand[(size_t)qi * CAP + slot] = make_float2(s, __int_as_float(m));
  };

  stage(0, 0);
  __syncthreads();

  for (int t = 0; t < NTZ; ++t) {
    const int cur = t & 1;
    if (t + 1 < NTZ) stage(t + 1, cur ^ 1);
    const char* kt = SMEM[cur];

    #pragma unroll
    for (int s = 0; s < 2; ++s) {
      const int ro = (s * 16 + lc) * 128;
      const bf16x8 ah0 = *reinterpret_cast<const bf16x8*>(kt + ro + o0);
      const bf16x8 ah1 = *reinterpret_cast<const bf16x8*>(kt + ro + o1);
      const bf16x8 al0 = *reinterpret_cast<const bf16x8*>(kt + 4096 + ro + o0);
      const bf16x8 al1 = *reinterpret_cast<const bf16x8*>(kt + 4096 + ro + o1);

      f32x4 acc0 = {0.f, 0.f, 0.f, 0.f};
      f32x4 acc1 = {0.f, 0.f, 0.f, 0.f};
      acc0 = __builtin_amdgcn_mfma_f32_16x16x32_bf16(ah0, q0h0, acc0, 0, 0, 0);
      acc1 = __builtin_amdgcn_mfma_f32_16x16x32_bf16(ah0, q1h0, acc1, 0, 0, 0);
      acc0 = __builtin_amdgcn_mfma_f32_16x16x32_bf16(ah1, q0h1, acc0, 0, 0, 0);
      acc1 = __builtin_amdgcn_mfma_f32_16x16x32_bf16(ah1, q1h1, acc1, 0, 0, 0);
      acc0 = __builtin_amdgcn_mfma_f32_16x16x32_bf16(al0, q0h0, acc0, 0, 0, 0);
      acc1 = __builtin_amdgcn_mfma_f32_16x16x32_bf16(al0, q1h0, acc1, 0, 0, 0);
      acc0 = __builtin_amdgcn_mfma_f32_16x16x32_bf16(al1, q0h1, acc0, 0, 0, 0);
      acc1 = __builtin_amdgcn_mfma_f32_16x16x32_bf16(al1, q1h1, acc1, 0, 0, 0);
      acc0 = __builtin_amdgcn_mfma_f32_16x16x32_bf16(ah0, q0l0, acc0, 0, 0, 0);
      acc1 = __builtin_amdgcn_mfma_f32_16x16x32_bf16(ah0, q1l0, acc1, 0, 0, 0);
      acc0 = __builtin_amdgcn_mfma_f32_16x16x32_bf16(ah1, q0l1, acc0, 0, 0, 0);
      acc1 = __builtin_amdgcn_mfma_f32_16x16x32_bf16(ah1, q1l1, acc1, 0, 0, 0);

      const int kb = kbase + t * KT + s * 16 + lg * 4;   // C/D: row = (lane>>4)*4 + reg
      const float g0 = fmaxf(fmaxf(acc0[0], acc0[1]), fmaxf(acc0[2], acc0[3]));
      if (g0 > tau0) {
        if (acc0[0] > tau0) emit(acc0[0], kb,     q0g);
        if (acc0[1] > tau0) emit(acc0[1], kb + 1, q0g);
        if (acc0[2] > tau0) emit(acc0[2], kb + 2, q0g);
        if (acc0[3] > tau0) emit(acc0[3], kb + 3, q0g);
      }
      const float g1 = fmaxf(fmaxf(acc1[0], acc1[1]), fmaxf(acc1[2], acc1[3]));
      if (g1 > tau1) {
        if (acc1[0] > tau1) emit(acc1[0], kb,     q1g);
        if (acc1[1] > tau1) emit(acc1[1], kb + 1, q1g);
        if (acc1[2] > tau1) emit(acc1[2], kb + 2, q1g);
        if (acc1[3] > tau1) emit(acc1[3], kb + 3, q1g);
      }
    }
    __syncthreads();
  }
}

// ====== merge: per-query top-9 of candidates + softmax + V gather ============
__global__ __launch_bounds__(256, 4) void merge_v(
    const float2* __restrict__ Cand, const int* __restrict__ Cnt,
    const float* __restrict__ Vt, float* __restrict__ Og) {
  __shared__ float2 CL[128][CAP];
  __shared__ float  Wls[128][K9];
  __shared__ int    Ils[128][K9];
  const int tid = threadIdx.x, b = blockIdx.y, qbase = blockIdx.x * 128;

  // cooperative load of all candidate slots (coalesced float2)
  {
    const float2* src = Cand + ((size_t)b * NPIX + qbase) * CAP;
    #pragma unroll
    for (int i = 0; i < 16; ++i) {
      const int idx = i * 256 + tid;           // 4096 entries
      CL[idx >> 5][idx & 31] = src[idx];
    }
  }
  __syncthreads();

  if (tid < 128) {
    const int qi = b * NPIX + qbase + tid;
    const int c = min(Cnt[qi], CAP);
    unsigned taken = 0;
    float mv[K9]; int mi[K9];
    #pragma unroll
    for (int r = 0; r < K9; ++r) {
      float bv = -3.4e38f; int bi = 0x7fffffff, bj = -1;
      for (int j = 0; j < c; ++j) {
        if (taken & (1u << j)) continue;
        const float v = CL[tid][j].x;
        const int   i = __float_as_int(CL[tid][j].y);
        if (v > bv || (v == bv && i < bi)) { bv = v; bi = i; bj = j; }
      }
      if (bj >= 0) { taken |= (1u << bj); mv[r] = bv; mi[r] = bi; }
      else         { mv[r] = -3.4e38f;    mi[r] = 0; }
    }
    const float mmax = mv[0];
    float e[K9]; float ssum = 0.f;
    #pragma unroll
    for (int r = 0; r < K9; ++r) { e[r] = expf(mv[r] - mmax); ssum += e[r]; }
    const float inv = 1.f / ssum;
    #pragma unroll
    for (int r = 0; r < K9; ++r) { Wls[tid][r] = e[r] * inv; Ils[tid][r] = mi[r]; }
  }
  __syncthreads();

  // 2 threads per query, 32 dims each; Vt rows are contiguous 256 B
  {
    const int q = tid >> 1, half = tid & 1;
    float o[32];
    #pragma unroll
    for (int c = 0; c < 32; ++c) o[c] = 0.f;
    #pragma unroll
    for (int r = 0; r < K9; ++r) {
      const float wgt = Wls[q][r];
      const int   m   = Ils[q][r];
      const float4* vp = reinterpret_cast<const float4*>(
          Vt + ((size_t)b * NPIX + m) * HD + half * 32);
      #pragma unroll
      for (int c4 = 0; c4 < 8; ++c4) {
        const float4 vv = vp[c4];
        o[c4 * 4]     = fmaf(wgt, vv.x, o[c4 * 4]);
        o[c4 * 4 + 1] = fmaf(wgt, vv.y, o[c4 * 4 + 1]);
        o[c4 * 4 + 2] = fmaf(wgt, vv.z, o[c4 * 4 + 2]);
        o[c4 * 4 + 3] = fmaf(wgt, vv.w, o[c4 * 4 + 3]);
      }
    }
    float* op = Og + (((size_t)b * NPIX) + qbase + q) * HD + half * 32;
    #pragma unroll
    for (int c4 = 0; c4 < 8; ++c4)
      *reinterpret_cast<float4*>(op + c4 * 4) =
        make_float4(o[c4 * 4], o[c4 * 4 + 1], o[c4 * 4 + 2], o[c4 * 4 + 3]);
  }
}

// ================= launch =====================================================
extern "C" void kernel_launch(void* const* d_in, const int* in_sizes, int n_in,
                              void* d_out, int out_size, void* d_ws, size_t ws_size,
                              hipStream_t stream) {
  const float* q = (const float*)d_in[0];
  const float* k = (const float*)d_in[1];
  const float* v = (const float*)d_in[2];
  float* o = (float*)d_out;

  const size_t asz = (size_t)B4 * NPIX * HD;          // 2.36M elems per array
  ushort_t* Qh = (ushort_t*)d_ws;
  ushort_t* Ql = Qh + asz;
  ushort_t* Kh = Ql + asz;
  ushort_t* Kl = Kh + asz;
  float*    Vt = (float*)(Kl + asz);                  // fp32 [b][n][d]
  float*    Pm = Vt + asz;                            // [b][n][4] quarter maxes
  int*      Ct = (int*)(Pm + (size_t)B4 * NPIX * 4);  // [b][n] counters
  float2*   Cd = (float2*)(Ct + (size_t)B4 * NPIX);   // [b][n][CAP] candidates

  const int nq = B4 * NPIX;
  zero_cnt<<<dim3((nq + 255) / 256), 256, 0, stream>>>(Ct, nq);
  prep_kernel<<<dim3(NPIX / 64, B4, 3), 256, 0, stream>>>(q, k, v, Qh, Ql, Kh, Kl, Vt);
  pass_max<<<dim3(NPIX / QBLK, B4, 4), 256, 0, stream>>>(Qh, Kh, Pm);
  pass_cand<<<dim3(NPIX / QBLK, B4, 4), 256, 0, stream>>>(Qh, Ql, Kh, Kl, Pm, Ct, Cd);
  merge_v<<<dim3(NPIX / 128, B4), 256, 0, stream>>>(Cd, Ct, Vt, o);
}